// Round 12
// baseline (4022.800 us; speedup 1.0000x reference)
//
#include <hip/hip_runtime.h>
#include <hip/hip_bf16.h>
#include <stdint.h>

// Problem dims (fixed): B=16, T=256, D=512, H=1024, L=512, V=32000
#define NSLOT 32          // workers per XCD group
#define GRID_LSTM 512     // oversubscribed; surplus blocks exit after registration

typedef __attribute__((ext_vector_type(4))) float f32x4;
typedef __attribute__((ext_vector_type(4))) int   i32x4;
typedef __attribute__((ext_vector_type(8))) __bf16 bf16x8;

__device__ __forceinline__ float sigf(float x) { return 1.f / (1.f + __expf(-x)); }
__device__ __forceinline__ float tanhf_fast(float x) { return 1.f - 2.f / (__expf(2.f * x) + 1.f); }

__device__ __forceinline__ unsigned short f2bf(float f) {
    union { __hip_bfloat16 h; unsigned short u; } cv;
    cv.h = __float2bfloat16(f);
    return cv.u;
}
__device__ __forceinline__ float bf2f(unsigned short u) {
    union { float f; unsigned v; } c; c.v = ((unsigned)u) << 16; return c.f;
}

// pack 4 unit-values (lanes n, n+4, n+8, n+12 of a 16-lane group) into u64 on lane n==0
__device__ __forceinline__ unsigned long long pack4(unsigned int h16) {
    unsigned int o4 = (unsigned int)__shfl_xor((int)h16, 4, 64);
    unsigned int p1 = h16 | (o4 << 16);
    unsigned int p2 = (unsigned int)__shfl_xor((int)p1, 8, 64);
    return (unsigned long long)p1 | ((unsigned long long)p2 << 32);
}

// L1-bypassing 16B load (fresh-address reads of L2 data within an XCD — r10-proven)
__device__ __forceinline__ bf16x8 load16_sc0(const unsigned short* p) {
    bf16x8 r;
    asm volatile("global_load_dwordx4 %0, %1, off sc0" : "=v"(r) : "v"(p));
    return r;
}

// ---- XCD-LOCAL flag barrier via L2-EXECUTED ATOMICS ----
// Default-scope global atomics execute at the issuing XCD's L2 (cross-XCD needs device scope).
// arrive: swap(target) — RMW at L2, no cache-visibility reasoning needed.
// wait:   add(0) with sc0 (return-old) — a true L2 read every poll (r11's sc0-load poll cached in L1).
__device__ __forceinline__ void lflag_arrive(unsigned* lf, int slot, unsigned target, int tid) {
    asm volatile("s_waitcnt vmcnt(0)" ::: "memory");   // ring stores completed in L2
    __syncthreads();                                   // all waves drained
    __builtin_amdgcn_sched_barrier(0);
    if (tid == 0) {
        unsigned* p = lf + slot * 16;
        asm volatile("global_atomic_swap %0, %1, off" :: "v"(p), "v"(target) : "memory");
    }
}
__device__ __forceinline__ void lflag_wait(unsigned* lf, unsigned target, int tid) {
    if (tid < NSLOT) {
        unsigned* p = lf + tid * 16;
        unsigned zero = 0u;
        long sp = 0;
        for (;;) {
            unsigned v;
            asm volatile("global_atomic_add %0, %1, %2, off sc0\n\ts_waitcnt vmcnt(0)"
                         : "=&v"(v) : "v"(p), "v"(zero) : "memory");
            if (v >= target) break;
            if (++sp > (1L << 16)) break;              // tight valve: fail FAST, not a timeout
        }
    }
    __syncthreads();
    __builtin_amdgcn_sched_barrier(0);
    asm volatile("" ::: "memory");
}

// startup: zero own LOCAL flag via L2 atomic (overwrites replay-stale line),
// then one-time L3 rendezvous on init-zeroed agent flags so nobody polls early.
__device__ __forceinline__ void startup_sync(unsigned* gf, unsigned* lf, int slot, int tid) {
    if (tid == 0) {
        unsigned* p = lf + slot * 16;
        unsigned z = 0u;
        asm volatile("global_atomic_swap %0, %1, off" :: "v"(p), "v"(z) : "memory");
    }
    asm volatile("s_waitcnt vmcnt(0)" ::: "memory");
    __syncthreads();
    if (tid == 0)
        __hip_atomic_store(&gf[slot * 16], 1u, __ATOMIC_RELAXED, __HIP_MEMORY_SCOPE_AGENT);
    if (tid < NSLOT) {
        long sp = 0;
        while (__hip_atomic_load(&gf[tid * 16], __ATOMIC_RELAXED, __HIP_MEMORY_SCOPE_AGENT) < 1u) {
            if (++sp > (1L << 20)) break;
        }
    }
    __syncthreads();
    asm volatile("" ::: "memory");
}

// registration: read physical XCD id, claim a slot on it
__device__ __forceinline__ void register_block(unsigned* regcnt, int* s_slot, int* s_xcd, int tid) {
    if (tid == 0) {
        unsigned x;
        asm volatile("s_getreg_b32 %0, hwreg(HW_REG_XCC_ID)" : "=s"(x));
        x &= 7u;
        unsigned my = __hip_atomic_fetch_add(&regcnt[x * 16], 1u,
                                             __ATOMIC_RELAXED, __HIP_MEMORY_SCOPE_AGENT);
        *s_xcd = (int)x;
        *s_slot = (my < NSLOT) ? (int)my : -1;
    }
    __syncthreads();
}

// ---------------- init: zero control words with AGENT stores (L3). Local flags zeroed in-kernel. ----------------
// ctrl layout (dwords): regcnt_e[8*16] | regcnt_d[8*16] | gf_e[8*32*16] | gf_d[8*32*16]
#define CTRL_DWORDS (128 + 128 + 4096 + 4096)
__global__ void init_kernel(unsigned* ctrl) {
    int id = blockIdx.x * 256 + threadIdx.x;
    if (id < CTRL_DWORDS)
        __hip_atomic_store(&ctrl[id], 0u, __ATOMIC_RELAXED, __HIP_MEMORY_SCOPE_AGENT);
}

// ---------------- x (fp32 [B,T,D]) -> bf16 same layout ----------------
__global__ __launch_bounds__(256) void cvt_x(const float* __restrict__ x, unsigned short* __restrict__ xb) {
    int id = blockIdx.x * 256 + threadIdx.x;          // 524288
    if (id >= 524288) return;
    f32x4 v = *(const f32x4*)(x + (size_t)id * 4);
    ushort4 r;
    r.x = f2bf(v.x); r.y = f2bf(v.y); r.z = f2bf(v.z); r.w = f2bf(v.w);
    *(ushort4*)(xb + (size_t)id * 4) = r;
}

// ---------------- gx GEMM: [4096,512](bf16) x [4096,512](fp32->bf16)^T -> bf16 [4096,4096] ----------------
__global__ __launch_bounds__(256) void gemm_gx(
        const unsigned short* __restrict__ A, const float* __restrict__ W,
        unsigned short* __restrict__ outb, int N) {
    __shared__ __align__(16) unsigned short lA[128 * 32];
    __shared__ __align__(16) unsigned short lB[128 * 32];
    const int tid = threadIdx.x, bid = blockIdx.x;
    const int mt = bid & 31, nt = bid >> 5;
    const int m0 = mt * 128, n0 = nt * 128;
    const int lane = tid & 63, wv = tid >> 6;
    const int wm = wv >> 1, wn = wv & 1;
    const int sr = tid >> 2, sc = (tid & 3) * 8;
    const int fr = lane & 15, kc = (lane >> 4) * 8;
    f32x4 acc[4][4];
    #pragma unroll
    for (int i = 0; i < 4; ++i)
        #pragma unroll
        for (int j = 0; j < 4; ++j) acc[i][j] = f32x4{0.f, 0.f, 0.f, 0.f};
    for (int k0 = 0; k0 < 512; k0 += 32) {
        __syncthreads();
        #pragma unroll
        for (int r0 = 0; r0 < 128; r0 += 64) {
            int r = sr + r0;
            *(i32x4*)(lA + r * 32 + sc) = *(const i32x4*)(A + (size_t)(m0 + r) * 512 + k0 + sc);
            f32x4 w0 = *(const f32x4*)(W + (size_t)(n0 + r) * 512 + k0 + sc);
            f32x4 w1 = *(const f32x4*)(W + (size_t)(n0 + r) * 512 + k0 + sc + 4);
            union { bf16x8 v; unsigned short u[8]; } cv;
            cv.u[0] = f2bf(w0.x); cv.u[1] = f2bf(w0.y); cv.u[2] = f2bf(w0.z); cv.u[3] = f2bf(w0.w);
            cv.u[4] = f2bf(w1.x); cv.u[5] = f2bf(w1.y); cv.u[6] = f2bf(w1.z); cv.u[7] = f2bf(w1.w);
            *(bf16x8*)(lB + r * 32 + sc) = cv.v;
        }
        __syncthreads();
        bf16x8 af[4], bfr[4];
        #pragma unroll
        for (int mi = 0; mi < 4; ++mi)
            af[mi] = *(const bf16x8*)(lA + (wm * 64 + mi * 16 + fr) * 32 + kc);
        #pragma unroll
        for (int ni = 0; ni < 4; ++ni)
            bfr[ni] = *(const bf16x8*)(lB + (wn * 64 + ni * 16 + fr) * 32 + kc);
        #pragma unroll
        for (int mi = 0; mi < 4; ++mi)
            #pragma unroll
            for (int ni = 0; ni < 4; ++ni)
                acc[mi][ni] = __builtin_amdgcn_mfma_f32_16x16x32_bf16(af[mi], bfr[ni], acc[mi][ni], 0, 0, 0);
    }
    const int orow = (lane >> 4) * 4;
    #pragma unroll
    for (int mi = 0; mi < 4; ++mi)
        #pragma unroll
        for (int ni = 0; ni < 4; ++ni) {
            int gm = m0 + wm * 64 + mi * 16 + orow;
            int gn = n0 + wn * 64 + ni * 16 + fr;
            #pragma unroll
            for (int j = 0; j < 4; ++j)
                outb[(size_t)(gm + j) * N + gn] = f2bf(acc[mi][ni][j]);
        }
}

// ---------------- encoder LSTM: XCD-group replicated, Whh in regs, gx hoisted, all-L2 exchange ----------------
__global__ __launch_bounds__(256, 1) void enc_kernel(
        const float* __restrict__ Whh, const float* __restrict__ bih, const float* __restrict__ bhh,
        const unsigned short* __restrict__ gxe /*[4096][4096] bf16*/,
        unsigned short* ring_e, unsigned* lflags_e,
        float* __restrict__ hT, unsigned* ctrl) {
    __shared__ int s_slot, s_xcd;
    const int tid = threadIdx.x;
    register_block(ctrl /*regcnt_e*/, &s_slot, &s_xcd, tid);
    const int slot = s_slot, xcd = s_xcd;
    if (slot < 0) return;
    unsigned* gf = ctrl + 256 + (size_t)xcd * NSLOT * 16;           // L3 startup flags (enc)
    unsigned* lf = lflags_e + (size_t)xcd * NSLOT * 16;             // L2-local step flags
    unsigned short* ringg = ring_e + (size_t)xcd * 2 * 16384;
    startup_sync(gf, lf, slot, tid);

    const int l = tid & 63, wv = tid >> 6;
    const int n = l & 15;
    const int kch = (l >> 4) * 8;
    const int ub = slot * 32 + wv * 8;
    const int colA = (n & 3) * 1024 + ub + (n >> 2);
    const int colB = colA + 4;
    bf16x8 wA[32], wB[32];
    #pragma unroll
    for (int kk = 0; kk < 32; ++kk) {
        {
            const float* src = Whh + (size_t)colA * 1024 + kk * 32 + kch;
            f32x4 w0 = *(const f32x4*)src, w1 = *(const f32x4*)(src + 4);
            union { bf16x8 v; unsigned short u[8]; } cv;
            cv.u[0] = f2bf(w0.x); cv.u[1] = f2bf(w0.y); cv.u[2] = f2bf(w0.z); cv.u[3] = f2bf(w0.w);
            cv.u[4] = f2bf(w1.x); cv.u[5] = f2bf(w1.y); cv.u[6] = f2bf(w1.z); cv.u[7] = f2bf(w1.w);
            wA[kk] = cv.v;
        }
        {
            const float* src = Whh + (size_t)colB * 1024 + kk * 32 + kch;
            f32x4 w0 = *(const f32x4*)src, w1 = *(const f32x4*)(src + 4);
            union { bf16x8 v; unsigned short u[8]; } cv;
            cv.u[0] = f2bf(w0.x); cv.u[1] = f2bf(w0.y); cv.u[2] = f2bf(w0.z); cv.u[3] = f2bf(w0.w);
            cv.u[4] = f2bf(w1.x); cv.u[5] = f2bf(w1.y); cv.u[6] = f2bf(w1.z); cv.u[7] = f2bf(w1.w);
            wB[kk] = cv.v;
        }
    }
    const float biasA = bih[colA] + bhh[colA];
    const float biasB = bih[colB] + bhh[colB];
    float cA0 = 0.f, cA1 = 0.f, cA2 = 0.f, cA3 = 0.f;
    float cB0 = 0.f, cB1 = 0.f, cB2 = 0.f, cB3 = 0.f;
    const bool b0 = (l & 1), b1 = (l & 2);
    const bool g0lane = ((l & 3) == 0);
    const int batbase = (l >> 4) * 4;
    for (int t = 0; t < 256; ++t) {
        float gA0, gA1, gA2, gA3, gB0, gB1, gB2, gB3;
        {
            const unsigned short* g0p = gxe + ((size_t)(batbase + 0) * 256 + t) * 4096;
            const unsigned short* g1p = gxe + ((size_t)(batbase + 1) * 256 + t) * 4096;
            const unsigned short* g2p = gxe + ((size_t)(batbase + 2) * 256 + t) * 4096;
            const unsigned short* g3p = gxe + ((size_t)(batbase + 3) * 256 + t) * 4096;
            gA0 = bf2f(g0p[colA]); gB0 = bf2f(g0p[colB]);
            gA1 = bf2f(g1p[colA]); gB1 = bf2f(g1p[colB]);
            gA2 = bf2f(g2p[colA]); gB2 = bf2f(g2p[colB]);
            gA3 = bf2f(g3p[colA]); gB3 = bf2f(g3p[colB]);
        }
        f32x4 aA0 = {0.f,0.f,0.f,0.f}, aA1 = {0.f,0.f,0.f,0.f};
        f32x4 aB0 = {0.f,0.f,0.f,0.f}, aB1 = {0.f,0.f,0.f,0.f};
        if (t > 0) {
            lflag_wait(lf, (unsigned)t, tid);
            const unsigned short* hb = ringg + ((t - 1) & 1) * 16384 + n * 32 + kch;
            bf16x8 ha[16];
            #pragma unroll
            for (int kk = 0; kk < 16; ++kk) ha[kk] = load16_sc0(hb + kk * 512);
            asm volatile("s_waitcnt vmcnt(0)" ::: "memory");
            __builtin_amdgcn_sched_barrier(0);
            bf16x8 ha2[16];
            #pragma unroll
            for (int kk = 0; kk < 16; ++kk) ha2[kk] = load16_sc0(hb + (16 + kk) * 512);
            #pragma unroll
            for (int kk = 0; kk < 16; ++kk) {
                aA0 = __builtin_amdgcn_mfma_f32_16x16x32_bf16(ha[kk], wA[kk], aA0, 0, 0, 0);
                aB0 = __builtin_amdgcn_mfma_f32_16x16x32_bf16(ha[kk], wB[kk], aB0, 0, 0, 0);
            }
            asm volatile("s_waitcnt vmcnt(0)" ::: "memory");
            __builtin_amdgcn_sched_barrier(0);
            #pragma unroll
            for (int kk = 0; kk < 16; ++kk) {
                aA1 = __builtin_amdgcn_mfma_f32_16x16x32_bf16(ha2[kk], wA[16 + kk], aA1, 0, 0, 0);
                aB1 = __builtin_amdgcn_mfma_f32_16x16x32_bf16(ha2[kk], wB[16 + kk], aB1, 0, 0, 0);
            }
        }
        unsigned short* sw = ringg + (t & 1) * 16384 + slot * 512 + wv * 8;
        #pragma unroll
        for (int j = 0; j < 4; ++j) {
            float gAj = (j == 0) ? gA0 : (j == 1) ? gA1 : (j == 2) ? gA2 : gA3;
            float gBj = (j == 0) ? gB0 : (j == 1) ? gB1 : (j == 2) ? gB2 : gB3;
            int bat = batbase + j;
            {
                float v = aA0[j] + aA1[j] + gAj + biasA;
                float vx1 = __shfl_xor(v, 1, 64), vx2 = __shfl_xor(v, 2, 64), vx3 = __shfl_xor(vx1, 2, 64);
                float iv = b1 ? (b0 ? vx3 : vx2) : (b0 ? vx1 : v);
                float fv = b1 ? (b0 ? vx2 : vx3) : (b0 ? v   : vx1);
                float gv = b1 ? (b0 ? vx1 : v  ) : (b0 ? vx3 : vx2);
                float ov = b1 ? (b0 ? v   : vx1) : (b0 ? vx2 : vx3);
                float cj = (j == 0) ? cA0 : (j == 1) ? cA1 : (j == 2) ? cA2 : cA3;
                float cn = sigf(fv) * cj + sigf(iv) * tanhf_fast(gv);
                if (j == 0) cA0 = cn; else if (j == 1) cA1 = cn; else if (j == 2) cA2 = cn; else cA3 = cn;
                float h = sigf(ov) * tanhf_fast(cn);
                unsigned long long pk = pack4((unsigned)f2bf(h));
                if ((l & 15) == 0) *(unsigned long long*)(sw + bat * 32) = pk;        // plain -> L2
                if (g0lane && xcd == 0 && t == 255) hT[bat * 1024 + ub + (n >> 2)] = h;
            }
            {
                float v = aB0[j] + aB1[j] + gBj + biasB;
                float vx1 = __shfl_xor(v, 1, 64), vx2 = __shfl_xor(v, 2, 64), vx3 = __shfl_xor(vx1, 2, 64);
                float iv = b1 ? (b0 ? vx3 : vx2) : (b0 ? vx1 : v);
                float fv = b1 ? (b0 ? vx2 : vx3) : (b0 ? v   : vx1);
                float gv = b1 ? (b0 ? vx1 : v  ) : (b0 ? vx3 : vx2);
                float ov = b1 ? (b0 ? v   : vx1) : (b0 ? vx2 : vx3);
                float cj = (j == 0) ? cB0 : (j == 1) ? cB1 : (j == 2) ? cB2 : cB3;
                float cn = sigf(fv) * cj + sigf(iv) * tanhf_fast(gv);
                if (j == 0) cB0 = cn; else if (j == 1) cB1 = cn; else if (j == 2) cB2 = cn; else cB3 = cn;
                float h = sigf(ov) * tanhf_fast(cn);
                unsigned long long pk = pack4((unsigned)f2bf(h));
                if ((l & 15) == 0) *(unsigned long long*)(sw + bat * 32 + 4) = pk;
                if (g0lane && xcd == 0 && t == 255) hT[bat * 1024 + ub + 4 + (n >> 2)] = h;
            }
        }
        lflag_arrive(lf, slot, (unsigned)(t + 1), tid);
    }
}

// ---------------- mu / logvar / z ----------------
__global__ __launch_bounds__(256) void mlz_kernel(
        const float* __restrict__ hT, const float* __restrict__ Wmu, const float* __restrict__ bmu,
        const float* __restrict__ Wlv, const float* __restrict__ blv, const float* __restrict__ eps,
        unsigned short* __restrict__ z_ring, float* __restrict__ out_tail) {
    int id = blockIdx.x * 256 + threadIdx.x;   // 8192 = b*512 + l
    int l = id & 511, b = id >> 9;
    const float* hb = hT + b * 1024;
    const float* wm = Wmu + (size_t)l * 1024;
    const float* wl = Wlv + (size_t)l * 1024;
    float am = 0.f, al = 0.f;
    for (int k = 0; k < 256; ++k) {
        f32x4 h4 = *(const f32x4*)(hb + k * 4);
        f32x4 m4 = *(const f32x4*)(wm + k * 4);
        f32x4 l4 = *(const f32x4*)(wl + k * 4);
        am += m4.x * h4.x + m4.y * h4.y + m4.z * h4.z + m4.w * h4.w;
        al += l4.x * h4.x + l4.y * h4.y + l4.z * h4.z + l4.w * h4.w;
    }
    float mu = fmaxf(am + bmu[l], 0.f);
    float lv = fmaxf(al + blv[l], 0.f);
    float z  = eps[id] * __expf(0.5f * lv) + mu;
    z_ring[(l >> 4) * 256 + b * 16 + (l & 15)] = f2bf(z);   // dec ring layout
    out_tail[id] = z;
    out_tail[8192 + id] = mu;
    out_tail[16384 + id] = lv;
}

// ---------------- decoder LSTM: XCD-group replicated, inline x-MFMA, all-L2 exchange ----------------
__global__ __launch_bounds__(256, 1) void dec_kernel(
        const float* __restrict__ Wih, const float* __restrict__ Whh,
        const float* __restrict__ bih, const float* __restrict__ bhh,
        const unsigned short* __restrict__ x_bf, const unsigned short* __restrict__ z_ring,
        unsigned short* ring_d, unsigned* lflags_d,
        unsigned short* __restrict__ ys_bf, unsigned* ctrl) {
    __shared__ int s_slot, s_xcd;
    const int tid = threadIdx.x;
    register_block(ctrl + 128 /*regcnt_d*/, &s_slot, &s_xcd, tid);
    const int slot = s_slot, xcd = s_xcd;
    if (slot < 0) return;
    unsigned* gf = ctrl + 256 + 4096 + (size_t)xcd * NSLOT * 16;     // L3 startup flags (dec)
    unsigned* lf = lflags_d + (size_t)xcd * NSLOT * 16;
    unsigned short* ringg = ring_d + (size_t)xcd * 2 * 8192;
    startup_sync(gf, lf, slot, tid);

    const int l = tid & 63, wv = tid >> 6;
    const int n = l & 15;
    const int kch = (l >> 4) * 8;
    const int ub = slot * 16 + wv * 4;
    const int col = (n & 3) * 512 + ub + (n >> 2);
    bf16x8 wf[32];
    #pragma unroll
    for (int kk = 0; kk < 32; ++kk) {
        const float* src = (kk < 16) ? (Wih + (size_t)col * 512 + kk * 32 + kch)
                                     : (Whh + (size_t)col * 512 + (kk - 16) * 32 + kch);
        f32x4 w0 = *(const f32x4*)src, w1 = *(const f32x4*)(src + 4);
        union { bf16x8 v; unsigned short u[8]; } cv;
        cv.u[0] = f2bf(w0.x); cv.u[1] = f2bf(w0.y); cv.u[2] = f2bf(w0.z); cv.u[3] = f2bf(w0.w);
        cv.u[4] = f2bf(w1.x); cv.u[5] = f2bf(w1.y); cv.u[6] = f2bf(w1.z); cv.u[7] = f2bf(w1.w);
        wf[kk] = cv.v;
    }
    const float bias = bih[col] + bhh[col];
    float c0 = 0.f, c1 = 0.f, c2 = 0.f, c3 = 0.f;
    const bool b0 = (l & 1), b1 = (l & 2);
    const bool g0lane = ((l & 3) == 0);
    const int batbase = (l >> 4) * 4;
    for (int t = 0; t < 256; ++t) {
        f32x4 acc0 = {0.f,0.f,0.f,0.f}, acc1 = {0.f,0.f,0.f,0.f};
        if (t > 0) {                                    // x-part overlaps wait
            const unsigned short* xrow = x_bf + ((size_t)n * 256 + (t - 1)) * 512 + kch;
            #pragma unroll
            for (int kk = 0; kk < 16; ++kk) {
                bf16x8 a = *(const bf16x8*)(xrow + kk * 32);
                acc0 = __builtin_amdgcn_mfma_f32_16x16x32_bf16(a, wf[kk], acc0, 0, 0, 0);
            }
            lflag_wait(lf, (unsigned)t, tid);
        }
        bf16x8 ha[16];
        if (t == 0) {
            #pragma unroll
            for (int kk = 0; kk < 16; ++kk) {
                int k = kk * 32 + kch;
                ha[kk] = *(const bf16x8*)(z_ring + (k >> 4) * 256 + n * 16 + (k & 15));
            }
        } else {
            const unsigned short* base = ringg + ((t - 1) & 1) * 8192;
            #pragma unroll
            for (int kk = 0; kk < 16; ++kk) {
                int k = kk * 32 + kch;
                ha[kk] = load16_sc0(base + (k >> 4) * 256 + n * 16 + (k & 15));
            }
            asm volatile("s_waitcnt vmcnt(0)" ::: "memory");
            __builtin_amdgcn_sched_barrier(0);
        }
        #pragma unroll
        for (int kk = 0; kk < 8; ++kk) {
            acc0 = __builtin_amdgcn_mfma_f32_16x16x32_bf16(ha[kk],     wf[16 + kk], acc0, 0, 0, 0);
            acc1 = __builtin_amdgcn_mfma_f32_16x16x32_bf16(ha[kk + 8], wf[24 + kk], acc1, 0, 0, 0);
        }
        unsigned short* sw = ringg + (t & 1) * 8192 + slot * 256 + wv * 4;
        #pragma unroll
        for (int j = 0; j < 4; ++j) {
            float v   = acc0[j] + acc1[j] + bias;
            float vx1 = __shfl_xor(v, 1, 64), vx2 = __shfl_xor(v, 2, 64), vx3 = __shfl_xor(vx1, 2, 64);
            float iv = b1 ? (b0 ? vx3 : vx2) : (b0 ? vx1 : v);
            float fv = b1 ? (b0 ? vx2 : vx3) : (b0 ? v   : vx1);
            float gv = b1 ? (b0 ? vx1 : v  ) : (b0 ? vx3 : vx2);
            float ov = b1 ? (b0 ? v   : vx1) : (b0 ? vx2 : vx3);
            float cj = (j == 0) ? c0 : (j == 1) ? c1 : (j == 2) ? c2 : c3;
            float cn = sigf(fv) * cj + sigf(iv) * tanhf_fast(gv);
            if (j == 0) c0 = cn; else if (j == 1) c1 = cn; else if (j == 2) c2 = cn; else c3 = cn;
            float h = sigf(ov) * tanhf_fast(cn);
            unsigned long long pk = pack4((unsigned)f2bf(h));
            int bat = batbase + j;
            if ((l & 15) == 0) *(unsigned long long*)(sw + bat * 16) = pk;    // plain -> L2
            if (g0lane && xcd == 0)
                ys_bf[((size_t)bat * 256 + t) * 512 + ub + (n >> 2)] = f2bf(h);
        }
        lflag_arrive(lf, slot, (unsigned)(t + 1), tid);
    }
}

// ---------------- logits GEMM (unchanged) ----------------
__global__ __launch_bounds__(256) void gemm_logits(
        const unsigned short* __restrict__ A, const float* __restrict__ W,
        const float* __restrict__ bout, float* __restrict__ out) {
    __shared__ __align__(16) unsigned short lA[128 * 32];
    __shared__ __align__(16) unsigned short lB[128 * 32];
    const int tid = threadIdx.x, bid = blockIdx.x;
    const int mt = bid & 31, nt = bid >> 5;
    const int m0 = mt * 128, n0 = nt * 128;
    const int lane = tid & 63, wv = tid >> 6;
    const int wm = wv >> 1, wn = wv & 1;
    const int sr = tid >> 2, sc = (tid & 3) * 8;
    const int fr = lane & 15, kc = (lane >> 4) * 8;
    f32x4 acc[4][4];
    #pragma unroll
    for (int i = 0; i < 4; ++i)
        #pragma unroll
        for (int j = 0; j < 4; ++j) acc[i][j] = f32x4{0.f, 0.f, 0.f, 0.f};
    for (int k0 = 0; k0 < 512; k0 += 32) {
        __syncthreads();
        #pragma unroll
        for (int r0 = 0; r0 < 128; r0 += 64) {
            int r = sr + r0;
            *(i32x4*)(lA + r * 32 + sc) = *(const i32x4*)(A + (size_t)(m0 + r) * 512 + k0 + sc);
            f32x4 w0 = *(const f32x4*)(W + (size_t)(n0 + r) * 512 + k0 + sc);
            f32x4 w1 = *(const f32x4*)(W + (size_t)(n0 + r) * 512 + k0 + sc + 4);
            union { bf16x8 v; unsigned short u[8]; } cv;
            cv.u[0] = f2bf(w0.x); cv.u[1] = f2bf(w0.y); cv.u[2] = f2bf(w0.z); cv.u[3] = f2bf(w0.w);
            cv.u[4] = f2bf(w1.x); cv.u[5] = f2bf(w1.y); cv.u[6] = f2bf(w1.z); cv.u[7] = f2bf(w1.w);
            *(bf16x8*)(lB + r * 32 + sc) = cv.v;
        }
        __syncthreads();
        bf16x8 af[4], bfr[4];
        #pragma unroll
        for (int mi = 0; mi < 4; ++mi)
            af[mi] = *(const bf16x8*)(lA + (wm * 64 + mi * 16 + fr) * 32 + kc);
        #pragma unroll
        for (int ni = 0; ni < 4; ++ni)
            bfr[ni] = *(const bf16x8*)(lB + (wn * 64 + ni * 16 + fr) * 32 + kc);
        #pragma unroll
        for (int mi = 0; mi < 4; ++mi)
            #pragma unroll
            for (int ni = 0; ni < 4; ++ni)
                acc[mi][ni] = __builtin_amdgcn_mfma_f32_16x16x32_bf16(af[mi], bfr[ni], acc[mi][ni], 0, 0, 0);
    }
    const int orow = (lane >> 4) * 4;
    #pragma unroll
    for (int mi = 0; mi < 4; ++mi)
        #pragma unroll
        for (int ni = 0; ni < 4; ++ni) {
            int gm = m0 + wm * 64 + mi * 16 + orow;
            int gn = n0 + wn * 64 + ni * 16 + fr;
            float bo = bout[gn];
            #pragma unroll
            for (int j = 0; j < 4; ++j)
                out[(size_t)(gm + j) * 32000 + gn] = acc[mi][ni][j] + bo;
        }
}

// ---------------- row softmax in-place (unchanged) ----------------
__global__ __launch_bounds__(512) void softmax_kernel(float* __restrict__ out) {
    __shared__ __align__(16) float row[32000];
    __shared__ float red[8];
    const int tid = threadIdx.x;
    float* p = out + (size_t)blockIdx.x * 32000;
    float mx = -3.4e38f;
    for (int c = tid; c < 8000; c += 512) {
        f32x4 v = *(const f32x4*)(p + c * 4);
        *(f32x4*)(row + c * 4) = v;
        mx = fmaxf(mx, fmaxf(fmaxf(v.x, v.y), fmaxf(v.z, v.w)));
    }
    #pragma unroll
    for (int o = 32; o; o >>= 1) mx = fmaxf(mx, __shfl_xor(mx, o, 64));
    if ((tid & 63) == 0) red[tid >> 6] = mx;
    __syncthreads();
    if (tid == 0) {
        float m = red[0];
        for (int i = 1; i < 8; ++i) m = fmaxf(m, red[i]);
        red[0] = m;
    }
    __syncthreads();
    mx = red[0];
    __syncthreads();
    float s = 0.f;
    for (int c = tid; c < 8000; c += 512) {
        f32x4 v = *(f32x4*)(row + c * 4);
        v.x = __expf(v.x - mx); v.y = __expf(v.y - mx);
        v.z = __expf(v.z - mx); v.w = __expf(v.w - mx);
        *(f32x4*)(row + c * 4) = v;
        s += v.x + v.y + v.z + v.w;
    }
    #pragma unroll
    for (int o = 32; o; o >>= 1) s += __shfl_xor(s, o, 64);
    if ((tid & 63) == 0) red[tid >> 6] = s;
    __syncthreads();
    if (tid == 0) {
        float t2 = 0.f;
        for (int i = 0; i < 8; ++i) t2 += red[i];
        red[0] = t2;
    }
    __syncthreads();
    float inv = 1.f / red[0];
    for (int c = tid; c < 8000; c += 512) {
        f32x4 v = *(f32x4*)(row + c * 4);
        v.x *= inv; v.y *= inv; v.z *= inv; v.w *= inv;
        *(f32x4*)(p + c * 4) = v;
    }
}

extern "C" void kernel_launch(void* const* d_in, const int* in_sizes, int n_in,
                              void* d_out, int out_size, void* d_ws, size_t ws_size,
                              hipStream_t stream) {
    (void)in_sizes; (void)n_in; (void)out_size; (void)ws_size;
    const float* x    = (const float*)d_in[0];
    const float* eps  = (const float*)d_in[1];
    const float* eWih = (const float*)d_in[2];
    const float* eWhh = (const float*)d_in[3];
    const float* ebih = (const float*)d_in[4];
    const float* ebhh = (const float*)d_in[5];
    const float* Wmu  = (const float*)d_in[6];
    const float* bmu  = (const float*)d_in[7];
    const float* Wlv  = (const float*)d_in[8];
    const float* blv  = (const float*)d_in[9];
    const float* dWih = (const float*)d_in[10];
    const float* dWhh = (const float*)d_in[11];
    const float* dbih = (const float*)d_in[12];
    const float* dbhh = (const float*)d_in[13];
    const float* Wout = (const float*)d_in[14];
    const float* bout = (const float*)d_in[15];
    float* out = (float*)d_out;

    // workspace layout (~41 MB)
    char* ws = (char*)d_ws;
    unsigned* ctrl         = (unsigned*)ws;                         // 64 KB reserved (init-zeroed)
    unsigned* lflags_e     = (unsigned*)(ws + 65536);               // 16 KB (zeroed in-kernel at L2)
    unsigned* lflags_d     = (unsigned*)(ws + 65536 + 16384);       // 16 KB (zeroed in-kernel at L2)
    unsigned short* x_bf   = (unsigned short*)(ws + 131072);        // 4 MB
    unsigned short* ysbf   = x_bf + (size_t)16 * 256 * 512;         // 4 MB
    unsigned short* ring_e = ysbf + (size_t)4096 * 512;             // 512 KB
    unsigned short* ring_d = ring_e + (size_t)8 * 2 * 16384;        // 256 KB
    unsigned short* z_ring = ring_d + (size_t)8 * 2 * 8192;         // 16 KB
    float* hT              = (float*)(z_ring + 8192);               // 64 KB
    unsigned short* gxe    = (unsigned short*)(hT + 16384);         // 32 MB

    hipLaunchKernelGGL(init_kernel, dim3(33), dim3(256), 0, stream, ctrl);
    hipLaunchKernelGGL(cvt_x, dim3(2048), dim3(256), 0, stream, x, x_bf);
    hipLaunchKernelGGL(gemm_gx, dim3(1024), dim3(256), 0, stream, x_bf, eWih, gxe, 4096);
    hipLaunchKernelGGL(enc_kernel, dim3(GRID_LSTM), dim3(256), 0, stream,
                       eWhh, ebih, ebhh, gxe, ring_e, lflags_e, hT, ctrl);
    hipLaunchKernelGGL(mlz_kernel, dim3(32), dim3(256), 0, stream,
                       hT, Wmu, bmu, Wlv, blv, eps, z_ring, out + 131072000);
    hipLaunchKernelGGL(dec_kernel, dim3(GRID_LSTM), dim3(256), 0, stream,
                       dWih, dWhh, dbih, dbhh, x_bf, z_ring, ring_d, lflags_d, ysbf, ctrl);
    hipLaunchKernelGGL(gemm_logits, dim3(8000), dim3(256), 0, stream, ysbf, Wout, bout, out);
    hipLaunchKernelGGL(softmax_kernel, dim3(4096), dim3(512), 0, stream, out);
}

// Round 13
// 3617.936 us; speedup vs baseline: 1.1119x; 1.1119x over previous
//
#include <hip/hip_runtime.h>
#include <hip/hip_bf16.h>
#include <stdint.h>

// Problem dims (fixed): B=16, T=256, D=512, H=1024, L=512, V=32000
#define NSLOT 32          // workers per XCD group
#define GRID_LSTM 512     // oversubscribed; surplus blocks exit after registration

typedef __attribute__((ext_vector_type(4))) float f32x4;
typedef __attribute__((ext_vector_type(4))) int   i32x4;
typedef __attribute__((ext_vector_type(8))) __bf16 bf16x8;

__device__ __forceinline__ float sigf(float x) { return 1.f / (1.f + __expf(-x)); }
__device__ __forceinline__ float tanhf_fast(float x) { return 1.f - 2.f / (__expf(2.f * x) + 1.f); }

__device__ __forceinline__ unsigned short f2bf(float f) {
    union { __hip_bfloat16 h; unsigned short u; } cv;
    cv.h = __float2bfloat16(f);
    return cv.u;
}
__device__ __forceinline__ float bf2f(unsigned short u) {
    union { float f; unsigned v; } c; c.v = ((unsigned)u) << 16; return c.f;
}

// pack 4 unit-values (lanes n, n+4, n+8, n+12 of a 16-lane group) into u64 on lane n==0
__device__ __forceinline__ unsigned long long pack4(unsigned int h16) {
    unsigned int o4 = (unsigned int)__shfl_xor((int)h16, 4, 64);
    unsigned int p1 = h16 | (o4 << 16);
    unsigned int p2 = (unsigned int)__shfl_xor((int)p1, 8, 64);
    return (unsigned long long)p1 | ((unsigned long long)p2 << 32);
}

// L1-bypassing 16B load (fresh-address reads of L2 data within an XCD — r10-proven)
__device__ __forceinline__ bf16x8 load16_sc0(const unsigned short* p) {
    bf16x8 r;
    asm volatile("global_load_dwordx4 %0, %1, off sc0" : "=v"(r) : "v"(p));
    return r;
}

// ---- L3 flag barrier (r10-proven): agent-scope flags; ring data coherent via shared L2 ----
__device__ __forceinline__ void flag_arrive(unsigned* flags, int slot, unsigned target, int tid) {
    asm volatile("s_waitcnt vmcnt(0)" ::: "memory");   // ring stores completed (L2)
    __syncthreads();
    if (tid == 0)
        __hip_atomic_store(&flags[slot * 16], target, __ATOMIC_RELAXED, __HIP_MEMORY_SCOPE_AGENT);
}
__device__ __forceinline__ void flag_wait(unsigned* flags, unsigned target, int tid) {
    if (tid < NSLOT) {
        long sp = 0;
        while (__hip_atomic_load(&flags[tid * 16], __ATOMIC_RELAXED, __HIP_MEMORY_SCOPE_AGENT) < target) {
            if (++sp > (1L << 20)) break;              // safety valve
        }
    }
    __syncthreads();
    __builtin_amdgcn_sched_barrier(0);
    asm volatile("" ::: "memory");
}

// registration: read physical XCD id, claim a slot on it
__device__ __forceinline__ void register_block(unsigned* regcnt, int* s_slot, int* s_xcd, int tid) {
    if (tid == 0) {
        unsigned x;
        asm volatile("s_getreg_b32 %0, hwreg(HW_REG_XCC_ID)" : "=s"(x));
        x &= 7u;
        unsigned my = __hip_atomic_fetch_add(&regcnt[x * 16], 1u,
                                             __ATOMIC_RELAXED, __HIP_MEMORY_SCOPE_AGENT);
        *s_xcd = (int)x;
        *s_slot = (my < NSLOT) ? (int)my : -1;
    }
    __syncthreads();
}

// ---------------- init: zero control words with AGENT stores (L3) ----------------
// ctrl layout (dwords): regcnt_e[8*16] | regcnt_d[8*16] | gf_e[8*32*16] | gf_d[8*32*16]
#define CTRL_DWORDS (128 + 128 + 4096 + 4096)
__global__ void init_kernel(unsigned* ctrl) {
    int id = blockIdx.x * 256 + threadIdx.x;
    if (id < CTRL_DWORDS)
        __hip_atomic_store(&ctrl[id], 0u, __ATOMIC_RELAXED, __HIP_MEMORY_SCOPE_AGENT);
}

// ---------------- x (fp32 [B,T,D]) -> bf16 same layout ----------------
__global__ __launch_bounds__(256) void cvt_x(const float* __restrict__ x, unsigned short* __restrict__ xb) {
    int id = blockIdx.x * 256 + threadIdx.x;          // 524288
    if (id >= 524288) return;
    f32x4 v = *(const f32x4*)(x + (size_t)id * 4);
    ushort4 r;
    r.x = f2bf(v.x); r.y = f2bf(v.y); r.z = f2bf(v.z); r.w = f2bf(v.w);
    *(ushort4*)(xb + (size_t)id * 4) = r;
}

// ---------------- Wout fp32 -> bf16 (into the gxe region, dead after enc) ----------------
__global__ __launch_bounds__(256) void cvt_wout(const float* __restrict__ w, unsigned short* __restrict__ o) {
    int id = blockIdx.x * 256 + threadIdx.x;          // 4,096,000 x ushort4
    if (id >= 4096000) return;
    f32x4 v = *(const f32x4*)(w + (size_t)id * 4);
    ushort4 r;
    r.x = f2bf(v.x); r.y = f2bf(v.y); r.z = f2bf(v.z); r.w = f2bf(v.w);
    *(ushort4*)(o + (size_t)id * 4) = r;
}

// ---------------- gx GEMM: [4096,512](bf16) x [4096,512](fp32->bf16)^T -> bf16 [4096,4096] ----------------
__global__ __launch_bounds__(256) void gemm_gx(
        const unsigned short* __restrict__ A, const float* __restrict__ W,
        unsigned short* __restrict__ outb, int N) {
    __shared__ __align__(16) unsigned short lA[128 * 32];
    __shared__ __align__(16) unsigned short lB[128 * 32];
    const int tid = threadIdx.x, bid = blockIdx.x;
    const int mt = bid & 31, nt = bid >> 5;
    const int m0 = mt * 128, n0 = nt * 128;
    const int lane = tid & 63, wv = tid >> 6;
    const int wm = wv >> 1, wn = wv & 1;
    const int sr = tid >> 2, sc = (tid & 3) * 8;
    const int fr = lane & 15, kc = (lane >> 4) * 8;
    f32x4 acc[4][4];
    #pragma unroll
    for (int i = 0; i < 4; ++i)
        #pragma unroll
        for (int j = 0; j < 4; ++j) acc[i][j] = f32x4{0.f, 0.f, 0.f, 0.f};
    for (int k0 = 0; k0 < 512; k0 += 32) {
        __syncthreads();
        #pragma unroll
        for (int r0 = 0; r0 < 128; r0 += 64) {
            int r = sr + r0;
            *(i32x4*)(lA + r * 32 + sc) = *(const i32x4*)(A + (size_t)(m0 + r) * 512 + k0 + sc);
            f32x4 w0 = *(const f32x4*)(W + (size_t)(n0 + r) * 512 + k0 + sc);
            f32x4 w1 = *(const f32x4*)(W + (size_t)(n0 + r) * 512 + k0 + sc + 4);
            union { bf16x8 v; unsigned short u[8]; } cv;
            cv.u[0] = f2bf(w0.x); cv.u[1] = f2bf(w0.y); cv.u[2] = f2bf(w0.z); cv.u[3] = f2bf(w0.w);
            cv.u[4] = f2bf(w1.x); cv.u[5] = f2bf(w1.y); cv.u[6] = f2bf(w1.z); cv.u[7] = f2bf(w1.w);
            *(bf16x8*)(lB + r * 32 + sc) = cv.v;
        }
        __syncthreads();
        bf16x8 af[4], bfr[4];
        #pragma unroll
        for (int mi = 0; mi < 4; ++mi)
            af[mi] = *(const bf16x8*)(lA + (wm * 64 + mi * 16 + fr) * 32 + kc);
        #pragma unroll
        for (int ni = 0; ni < 4; ++ni)
            bfr[ni] = *(const bf16x8*)(lB + (wn * 64 + ni * 16 + fr) * 32 + kc);
        #pragma unroll
        for (int mi = 0; mi < 4; ++mi)
            #pragma unroll
            for (int ni = 0; ni < 4; ++ni)
                acc[mi][ni] = __builtin_amdgcn_mfma_f32_16x16x32_bf16(af[mi], bfr[ni], acc[mi][ni], 0, 0, 0);
    }
    const int orow = (lane >> 4) * 4;
    #pragma unroll
    for (int mi = 0; mi < 4; ++mi)
        #pragma unroll
        for (int ni = 0; ni < 4; ++ni) {
            int gm = m0 + wm * 64 + mi * 16 + orow;
            int gn = n0 + wn * 64 + ni * 16 + fr;
            #pragma unroll
            for (int j = 0; j < 4; ++j)
                outb[(size_t)(gm + j) * N + gn] = f2bf(acc[mi][ni][j]);
        }
}

// ---------------- encoder LSTM: XCD-group replicated, Whh in regs, gx hoisted, L2 rings (r10) ----------------
__global__ __launch_bounds__(256, 1) void enc_kernel(
        const float* __restrict__ Whh, const float* __restrict__ bih, const float* __restrict__ bhh,
        const unsigned short* __restrict__ gxe /*[4096][4096] bf16*/,
        unsigned short* ring_e, float* __restrict__ hT, unsigned* ctrl) {
    __shared__ int s_slot, s_xcd;
    const int tid = threadIdx.x;
    register_block(ctrl /*regcnt_e*/, &s_slot, &s_xcd, tid);
    const int slot = s_slot, xcd = s_xcd;
    if (slot < 0) return;
    unsigned* flags = ctrl + 256 + (size_t)xcd * NSLOT * 16;        // L3 flags (enc)
    unsigned short* ringg = ring_e + (size_t)xcd * 2 * 16384;

    const int l = tid & 63, wv = tid >> 6;
    const int n = l & 15;
    const int kch = (l >> 4) * 8;
    const int ub = slot * 32 + wv * 8;
    const int colA = (n & 3) * 1024 + ub + (n >> 2);
    const int colB = colA + 4;
    bf16x8 wA[32], wB[32];
    #pragma unroll
    for (int kk = 0; kk < 32; ++kk) {
        {
            const float* src = Whh + (size_t)colA * 1024 + kk * 32 + kch;
            f32x4 w0 = *(const f32x4*)src, w1 = *(const f32x4*)(src + 4);
            union { bf16x8 v; unsigned short u[8]; } cv;
            cv.u[0] = f2bf(w0.x); cv.u[1] = f2bf(w0.y); cv.u[2] = f2bf(w0.z); cv.u[3] = f2bf(w0.w);
            cv.u[4] = f2bf(w1.x); cv.u[5] = f2bf(w1.y); cv.u[6] = f2bf(w1.z); cv.u[7] = f2bf(w1.w);
            wA[kk] = cv.v;
        }
        {
            const float* src = Whh + (size_t)colB * 1024 + kk * 32 + kch;
            f32x4 w0 = *(const f32x4*)src, w1 = *(const f32x4*)(src + 4);
            union { bf16x8 v; unsigned short u[8]; } cv;
            cv.u[0] = f2bf(w0.x); cv.u[1] = f2bf(w0.y); cv.u[2] = f2bf(w0.z); cv.u[3] = f2bf(w0.w);
            cv.u[4] = f2bf(w1.x); cv.u[5] = f2bf(w1.y); cv.u[6] = f2bf(w1.z); cv.u[7] = f2bf(w1.w);
            wB[kk] = cv.v;
        }
    }
    const float biasA = bih[colA] + bhh[colA];
    const float biasB = bih[colB] + bhh[colB];
    float cA0 = 0.f, cA1 = 0.f, cA2 = 0.f, cA3 = 0.f;
    float cB0 = 0.f, cB1 = 0.f, cB2 = 0.f, cB3 = 0.f;
    const bool b0 = (l & 1), b1 = (l & 2);
    const bool g0lane = ((l & 3) == 0);
    const int batbase = (l >> 4) * 4;
    for (int t = 0; t < 256; ++t) {
        float gA0, gA1, gA2, gA3, gB0, gB1, gB2, gB3;
        {
            const unsigned short* g0p = gxe + ((size_t)(batbase + 0) * 256 + t) * 4096;
            const unsigned short* g1p = gxe + ((size_t)(batbase + 1) * 256 + t) * 4096;
            const unsigned short* g2p = gxe + ((size_t)(batbase + 2) * 256 + t) * 4096;
            const unsigned short* g3p = gxe + ((size_t)(batbase + 3) * 256 + t) * 4096;
            gA0 = bf2f(g0p[colA]); gB0 = bf2f(g0p[colB]);
            gA1 = bf2f(g1p[colA]); gB1 = bf2f(g1p[colB]);
            gA2 = bf2f(g2p[colA]); gB2 = bf2f(g2p[colB]);
            gA3 = bf2f(g3p[colA]); gB3 = bf2f(g3p[colB]);
        }
        f32x4 aA0 = {0.f,0.f,0.f,0.f}, aA1 = {0.f,0.f,0.f,0.f};
        f32x4 aB0 = {0.f,0.f,0.f,0.f}, aB1 = {0.f,0.f,0.f,0.f};
        if (t > 0) {
            flag_wait(flags, (unsigned)t, tid);
            const unsigned short* hb = ringg + ((t - 1) & 1) * 16384 + n * 32 + kch;
            bf16x8 ha[16];
            #pragma unroll
            for (int kk = 0; kk < 16; ++kk) ha[kk] = load16_sc0(hb + kk * 512);
            asm volatile("s_waitcnt vmcnt(0)" ::: "memory");
            __builtin_amdgcn_sched_barrier(0);
            bf16x8 ha2[16];
            #pragma unroll
            for (int kk = 0; kk < 16; ++kk) ha2[kk] = load16_sc0(hb + (16 + kk) * 512);
            #pragma unroll
            for (int kk = 0; kk < 16; ++kk) {
                aA0 = __builtin_amdgcn_mfma_f32_16x16x32_bf16(ha[kk], wA[kk], aA0, 0, 0, 0);
                aB0 = __builtin_amdgcn_mfma_f32_16x16x32_bf16(ha[kk], wB[kk], aB0, 0, 0, 0);
            }
            asm volatile("s_waitcnt vmcnt(0)" ::: "memory");
            __builtin_amdgcn_sched_barrier(0);
            #pragma unroll
            for (int kk = 0; kk < 16; ++kk) {
                aA1 = __builtin_amdgcn_mfma_f32_16x16x32_bf16(ha2[kk], wA[16 + kk], aA1, 0, 0, 0);
                aB1 = __builtin_amdgcn_mfma_f32_16x16x32_bf16(ha2[kk], wB[16 + kk], aB1, 0, 0, 0);
            }
        }
        unsigned short* sw = ringg + (t & 1) * 16384 + slot * 512 + wv * 8;
        #pragma unroll
        for (int j = 0; j < 4; ++j) {
            float gAj = (j == 0) ? gA0 : (j == 1) ? gA1 : (j == 2) ? gA2 : gA3;
            float gBj = (j == 0) ? gB0 : (j == 1) ? gB1 : (j == 2) ? gB2 : gB3;
            int bat = batbase + j;
            {
                float v = aA0[j] + aA1[j] + gAj + biasA;
                float vx1 = __shfl_xor(v, 1, 64), vx2 = __shfl_xor(v, 2, 64), vx3 = __shfl_xor(vx1, 2, 64);
                float iv = b1 ? (b0 ? vx3 : vx2) : (b0 ? vx1 : v);
                float fv = b1 ? (b0 ? vx2 : vx3) : (b0 ? v   : vx1);
                float gv = b1 ? (b0 ? vx1 : v  ) : (b0 ? vx3 : vx2);
                float ov = b1 ? (b0 ? v   : vx1) : (b0 ? vx2 : vx3);
                float cj = (j == 0) ? cA0 : (j == 1) ? cA1 : (j == 2) ? cA2 : cA3;
                float cn = sigf(fv) * cj + sigf(iv) * tanhf_fast(gv);
                if (j == 0) cA0 = cn; else if (j == 1) cA1 = cn; else if (j == 2) cA2 = cn; else cA3 = cn;
                float h = sigf(ov) * tanhf_fast(cn);
                unsigned long long pk = pack4((unsigned)f2bf(h));
                if ((l & 15) == 0) *(unsigned long long*)(sw + bat * 32) = pk;        // plain -> L2
                if (g0lane && xcd == 0 && t == 255) hT[bat * 1024 + ub + (n >> 2)] = h;
            }
            {
                float v = aB0[j] + aB1[j] + gBj + biasB;
                float vx1 = __shfl_xor(v, 1, 64), vx2 = __shfl_xor(v, 2, 64), vx3 = __shfl_xor(vx1, 2, 64);
                float iv = b1 ? (b0 ? vx3 : vx2) : (b0 ? vx1 : v);
                float fv = b1 ? (b0 ? vx2 : vx3) : (b0 ? v   : vx1);
                float gv = b1 ? (b0 ? vx1 : v  ) : (b0 ? vx3 : vx2);
                float ov = b1 ? (b0 ? v   : vx1) : (b0 ? vx2 : vx3);
                float cj = (j == 0) ? cB0 : (j == 1) ? cB1 : (j == 2) ? cB2 : cB3;
                float cn = sigf(fv) * cj + sigf(iv) * tanhf_fast(gv);
                if (j == 0) cB0 = cn; else if (j == 1) cB1 = cn; else if (j == 2) cB2 = cn; else cB3 = cn;
                float h = sigf(ov) * tanhf_fast(cn);
                unsigned long long pk = pack4((unsigned)f2bf(h));
                if ((l & 15) == 0) *(unsigned long long*)(sw + bat * 32 + 4) = pk;
                if (g0lane && xcd == 0 && t == 255) hT[bat * 1024 + ub + 4 + (n >> 2)] = h;
            }
        }
        flag_arrive(flags, slot, (unsigned)(t + 1), tid);
    }
}

// ---------------- mu / logvar / z ----------------
__global__ __launch_bounds__(256) void mlz_kernel(
        const float* __restrict__ hT, const float* __restrict__ Wmu, const float* __restrict__ bmu,
        const float* __restrict__ Wlv, const float* __restrict__ blv, const float* __restrict__ eps,
        unsigned short* __restrict__ z_ring, float* __restrict__ out_tail) {
    int id = blockIdx.x * 256 + threadIdx.x;   // 8192 = b*512 + l
    int l = id & 511, b = id >> 9;
    const float* hb = hT + b * 1024;
    const float* wm = Wmu + (size_t)l * 1024;
    const float* wl = Wlv + (size_t)l * 1024;
    float am = 0.f, al = 0.f;
    for (int k = 0; k < 256; ++k) {
        f32x4 h4 = *(const f32x4*)(hb + k * 4);
        f32x4 m4 = *(const f32x4*)(wm + k * 4);
        f32x4 l4 = *(const f32x4*)(wl + k * 4);
        am += m4.x * h4.x + m4.y * h4.y + m4.z * h4.z + m4.w * h4.w;
        al += l4.x * h4.x + l4.y * h4.y + l4.z * h4.z + l4.w * h4.w;
    }
    float mu = fmaxf(am + bmu[l], 0.f);
    float lv = fmaxf(al + blv[l], 0.f);
    float z  = eps[id] * __expf(0.5f * lv) + mu;
    z_ring[(l >> 4) * 256 + b * 16 + (l & 15)] = f2bf(z);   // dec ring layout
    out_tail[id] = z;
    out_tail[8192 + id] = mu;
    out_tail[16384 + id] = lv;
}

// ---------------- decoder LSTM: XCD-group replicated, inline x-MFMA, L2 rings (r10) ----------------
__global__ __launch_bounds__(256, 1) void dec_kernel(
        const float* __restrict__ Wih, const float* __restrict__ Whh,
        const float* __restrict__ bih, const float* __restrict__ bhh,
        const unsigned short* __restrict__ x_bf, const unsigned short* __restrict__ z_ring,
        unsigned short* ring_d, unsigned short* __restrict__ ys_bf, unsigned* ctrl) {
    __shared__ int s_slot, s_xcd;
    const int tid = threadIdx.x;
    register_block(ctrl + 128 /*regcnt_d*/, &s_slot, &s_xcd, tid);
    const int slot = s_slot, xcd = s_xcd;
    if (slot < 0) return;
    unsigned* flags = ctrl + 256 + 4096 + (size_t)xcd * NSLOT * 16;  // L3 flags (dec)
    unsigned short* ringg = ring_d + (size_t)xcd * 2 * 8192;

    const int l = tid & 63, wv = tid >> 6;
    const int n = l & 15;
    const int kch = (l >> 4) * 8;
    const int ub = slot * 16 + wv * 4;
    const int col = (n & 3) * 512 + ub + (n >> 2);
    bf16x8 wf[32];
    #pragma unroll
    for (int kk = 0; kk < 32; ++kk) {
        const float* src = (kk < 16) ? (Wih + (size_t)col * 512 + kk * 32 + kch)
                                     : (Whh + (size_t)col * 512 + (kk - 16) * 32 + kch);
        f32x4 w0 = *(const f32x4*)src, w1 = *(const f32x4*)(src + 4);
        union { bf16x8 v; unsigned short u[8]; } cv;
        cv.u[0] = f2bf(w0.x); cv.u[1] = f2bf(w0.y); cv.u[2] = f2bf(w0.z); cv.u[3] = f2bf(w0.w);
        cv.u[4] = f2bf(w1.x); cv.u[5] = f2bf(w1.y); cv.u[6] = f2bf(w1.z); cv.u[7] = f2bf(w1.w);
        wf[kk] = cv.v;
    }
    const float bias = bih[col] + bhh[col];
    float c0 = 0.f, c1 = 0.f, c2 = 0.f, c3 = 0.f;
    const bool b0 = (l & 1), b1 = (l & 2);
    const bool g0lane = ((l & 3) == 0);
    const int batbase = (l >> 4) * 4;
    for (int t = 0; t < 256; ++t) {
        f32x4 acc0 = {0.f,0.f,0.f,0.f}, acc1 = {0.f,0.f,0.f,0.f};
        if (t > 0) {                                    // x-part overlaps wait
            const unsigned short* xrow = x_bf + ((size_t)n * 256 + (t - 1)) * 512 + kch;
            #pragma unroll
            for (int kk = 0; kk < 16; ++kk) {
                bf16x8 a = *(const bf16x8*)(xrow + kk * 32);
                acc0 = __builtin_amdgcn_mfma_f32_16x16x32_bf16(a, wf[kk], acc0, 0, 0, 0);
            }
            flag_wait(flags, (unsigned)t, tid);
        }
        bf16x8 ha[16];
        if (t == 0) {
            #pragma unroll
            for (int kk = 0; kk < 16; ++kk) {
                int k = kk * 32 + kch;
                ha[kk] = *(const bf16x8*)(z_ring + (k >> 4) * 256 + n * 16 + (k & 15));
            }
        } else {
            const unsigned short* base = ringg + ((t - 1) & 1) * 8192;
            #pragma unroll
            for (int kk = 0; kk < 16; ++kk) {
                int k = kk * 32 + kch;
                ha[kk] = load16_sc0(base + (k >> 4) * 256 + n * 16 + (k & 15));
            }
            asm volatile("s_waitcnt vmcnt(0)" ::: "memory");
            __builtin_amdgcn_sched_barrier(0);
        }
        #pragma unroll
        for (int kk = 0; kk < 8; ++kk) {
            acc0 = __builtin_amdgcn_mfma_f32_16x16x32_bf16(ha[kk],     wf[16 + kk], acc0, 0, 0, 0);
            acc1 = __builtin_amdgcn_mfma_f32_16x16x32_bf16(ha[kk + 8], wf[24 + kk], acc1, 0, 0, 0);
        }
        unsigned short* sw = ringg + (t & 1) * 8192 + slot * 256 + wv * 4;
        #pragma unroll
        for (int j = 0; j < 4; ++j) {
            float v   = acc0[j] + acc1[j] + bias;
            float vx1 = __shfl_xor(v, 1, 64), vx2 = __shfl_xor(v, 2, 64), vx3 = __shfl_xor(vx1, 2, 64);
            float iv = b1 ? (b0 ? vx3 : vx2) : (b0 ? vx1 : v);
            float fv = b1 ? (b0 ? vx2 : vx3) : (b0 ? v   : vx1);
            float gv = b1 ? (b0 ? vx1 : v  ) : (b0 ? vx3 : vx2);
            float ov = b1 ? (b0 ? v   : vx1) : (b0 ? vx2 : vx3);
            float cj = (j == 0) ? c0 : (j == 1) ? c1 : (j == 2) ? c2 : c3;
            float cn = sigf(fv) * cj + sigf(iv) * tanhf_fast(gv);
            if (j == 0) c0 = cn; else if (j == 1) c1 = cn; else if (j == 2) c2 = cn; else c3 = cn;
            float h = sigf(ov) * tanhf_fast(cn);
            unsigned long long pk = pack4((unsigned)f2bf(h));
            int bat = batbase + j;
            if ((l & 15) == 0) *(unsigned long long*)(sw + bat * 16) = pk;    // plain -> L2
            if (g0lane && xcd == 0)
                ys_bf[((size_t)bat * 256 + t) * 512 + ub + (n >> 2)] = f2bf(h);
        }
        flag_arrive(flags, slot, (unsigned)(t + 1), tid);
    }
}

// ---------------- logits GEMM: [4096,512]x[512,32000], BOTH operands bf16 (W pre-converted) ----------------
__global__ __launch_bounds__(256) void gemm_logits(
        const unsigned short* __restrict__ A, const unsigned short* __restrict__ Wb,
        const float* __restrict__ bout, float* __restrict__ out) {
    __shared__ __align__(16) unsigned short lA[128 * 32];
    __shared__ __align__(16) unsigned short lB[128 * 32];
    const int tid = threadIdx.x, bid = blockIdx.x;
    const int mt = bid & 31, nt = bid >> 5;           // m fastest: consecutive blocks share W-panel
    const int m0 = mt * 128, n0 = nt * 128;
    const int lane = tid & 63, wv = tid >> 6;
    const int wm = wv >> 1, wn = wv & 1;
    const int sr = tid >> 2, sc = (tid & 3) * 8;
    const int fr = lane & 15, kc = (lane >> 4) * 8;
    f32x4 acc[4][4];
    #pragma unroll
    for (int i = 0; i < 4; ++i)
        #pragma unroll
        for (int j = 0; j < 4; ++j) acc[i][j] = f32x4{0.f, 0.f, 0.f, 0.f};
    for (int k0 = 0; k0 < 512; k0 += 32) {
        __syncthreads();
        #pragma unroll
        for (int r0 = 0; r0 < 128; r0 += 64) {
            int r = sr + r0;
            *(i32x4*)(lA + r * 32 + sc) = *(const i32x4*)(A + (size_t)(m0 + r) * 512 + k0 + sc);
            *(i32x4*)(lB + r * 32 + sc) = *(const i32x4*)(Wb + (size_t)(n0 + r) * 512 + k0 + sc);
        }
        __syncthreads();
        bf16x8 af[4], bfr[4];
        #pragma unroll
        for (int mi = 0; mi < 4; ++mi)
            af[mi] = *(const bf16x8*)(lA + (wm * 64 + mi * 16 + fr) * 32 + kc);
        #pragma unroll
        for (int ni = 0; ni < 4; ++ni)
            bfr[ni] = *(const bf16x8*)(lB + (wn * 64 + ni * 16 + fr) * 32 + kc);
        #pragma unroll
        for (int mi = 0; mi < 4; ++mi)
            #pragma unroll
            for (int ni = 0; ni < 4; ++ni)
                acc[mi][ni] = __builtin_amdgcn_mfma_f32_16x16x32_bf16(af[mi], bfr[ni], acc[mi][ni], 0, 0, 0);
    }
    const int orow = (lane >> 4) * 4;
    #pragma unroll
    for (int mi = 0; mi < 4; ++mi)
        #pragma unroll
        for (int ni = 0; ni < 4; ++ni) {
            int gm = m0 + wm * 64 + mi * 16 + orow;
            int gn = n0 + wn * 64 + ni * 16 + fr;
            float bo = bout[gn];
            #pragma unroll
            for (int j = 0; j < 4; ++j)
                out[(size_t)(gm + j) * 32000 + gn] = acc[mi][ni][j] + bo;
        }
}

// ---------------- row softmax in-place (LDS row buffer: 1 read + 1 write of HBM) ----------------
__global__ __launch_bounds__(512) void softmax_kernel(float* __restrict__ out) {
    __shared__ __align__(16) float row[32000];
    __shared__ float red[8];
    const int tid = threadIdx.x;
    float* p = out + (size_t)blockIdx.x * 32000;
    float mx = -3.4e38f;
    for (int c = tid; c < 8000; c += 512) {
        f32x4 v = *(const f32x4*)(p + c * 4);
        *(f32x4*)(row + c * 4) = v;
        mx = fmaxf(mx, fmaxf(fmaxf(v.x, v.y), fmaxf(v.z, v.w)));
    }
    #pragma unroll
    for (int o = 32; o; o >>= 1) mx = fmaxf(mx, __shfl_xor(mx, o, 64));
    if ((tid & 63) == 0) red[tid >> 6] = mx;
    __syncthreads();
    if (tid == 0) {
        float m = red[0];
        for (int i = 1; i < 8; ++i) m = fmaxf(m, red[i]);
        red[0] = m;
    }
    __syncthreads();
    mx = red[0];
    __syncthreads();
    float s = 0.f;
    for (int c = tid; c < 8000; c += 512) {
        f32x4 v = *(f32x4*)(row + c * 4);
        v.x = __expf(v.x - mx); v.y = __expf(v.y - mx);
        v.z = __expf(v.z - mx); v.w = __expf(v.w - mx);
        *(f32x4*)(row + c * 4) = v;
        s += v.x + v.y + v.z + v.w;
    }
    #pragma unroll
    for (int o = 32; o; o >>= 1) s += __shfl_xor(s, o, 64);
    if ((tid & 63) == 0) red[tid >> 6] = s;
    __syncthreads();
    if (tid == 0) {
        float t2 = 0.f;
        for (int i = 0; i < 8; ++i) t2 += red[i];
        red[0] = t2;
    }
    __syncthreads();
    float inv = 1.f / red[0];
    for (int c = tid; c < 8000; c += 512) {
        f32x4 v = *(f32x4*)(row + c * 4);
        v.x *= inv; v.y *= inv; v.z *= inv; v.w *= inv;
        *(f32x4*)(p + c * 4) = v;
    }
}

extern "C" void kernel_launch(void* const* d_in, const int* in_sizes, int n_in,
                              void* d_out, int out_size, void* d_ws, size_t ws_size,
                              hipStream_t stream) {
    (void)in_sizes; (void)n_in; (void)out_size; (void)ws_size;
    const float* x    = (const float*)d_in[0];
    const float* eps  = (const float*)d_in[1];
    const float* eWih = (const float*)d_in[2];
    const float* eWhh = (const float*)d_in[3];
    const float* ebih = (const float*)d_in[4];
    const float* ebhh = (const float*)d_in[5];
    const float* Wmu  = (const float*)d_in[6];
    const float* bmu  = (const float*)d_in[7];
    const float* Wlv  = (const float*)d_in[8];
    const float* blv  = (const float*)d_in[9];
    const float* dWih = (const float*)d_in[10];
    const float* dWhh = (const float*)d_in[11];
    const float* dbih = (const float*)d_in[12];
    const float* dbhh = (const float*)d_in[13];
    const float* Wout = (const float*)d_in[14];
    const float* bout = (const float*)d_in[15];
    float* out = (float*)d_out;

    // workspace layout (~42 MB)
    char* ws = (char*)d_ws;
    unsigned* ctrl         = (unsigned*)ws;                         // 64 KB reserved (init-zeroed)
    unsigned short* x_bf   = (unsigned short*)(ws + 65536);         // 4 MB
    unsigned short* ysbf   = x_bf + (size_t)16 * 256 * 512;         // 4 MB
    unsigned short* ring_e = ysbf + (size_t)4096 * 512;             // 512 KB
    unsigned short* ring_d = ring_e + (size_t)8 * 2 * 16384;        // 256 KB
    unsigned short* z_ring = ring_d + (size_t)8 * 2 * 8192;         // 16 KB
    float* hT              = (float*)(z_ring + 8192);               // 64 KB
    unsigned short* gxe    = (unsigned short*)(hT + 16384);         // 33.5 MB (gxe; reused as wo_bf after enc)
    unsigned short* wo_bf  = gxe;                                   // 32000*512*2 = 32.8 MB

    hipLaunchKernelGGL(init_kernel, dim3(33), dim3(256), 0, stream, ctrl);
    hipLaunchKernelGGL(cvt_x, dim3(2048), dim3(256), 0, stream, x, x_bf);
    hipLaunchKernelGGL(gemm_gx, dim3(1024), dim3(256), 0, stream, x_bf, eWih, gxe, 4096);
    hipLaunchKernelGGL(enc_kernel, dim3(GRID_LSTM), dim3(256), 0, stream,
                       eWhh, ebih, ebhh, gxe, ring_e, hT, ctrl);
    hipLaunchKernelGGL(cvt_wout, dim3(16000), dim3(256), 0, stream, Wout, wo_bf);   // gxe dead after enc
    hipLaunchKernelGGL(mlz_kernel, dim3(32), dim3(256), 0, stream,
                       hT, Wmu, bmu, Wlv, blv, eps, z_ring, out + 131072000);
    hipLaunchKernelGGL(dec_kernel, dim3(GRID_LSTM), dim3(256), 0, stream,
                       dWih, dWhh, dbih, dbhh, x_bf, z_ring, ring_d, ysbf, ctrl);
    hipLaunchKernelGGL(gemm_logits, dim3(8000), dim3(256), 0, stream, ysbf, wo_bf, bout, out);
    hipLaunchKernelGGL(softmax_kernel, dim3(4096), dim3(512), 0, stream, out);
}

// Round 14
// 3543.224 us; speedup vs baseline: 1.1354x; 1.0211x over previous
//
#include <hip/hip_runtime.h>
#include <hip/hip_bf16.h>
#include <stdint.h>

// Problem dims (fixed): B=16, T=256, D=512, H=1024, L=512, V=32000
#define NSLOT 32          // workers per XCD group
#define GRID_LSTM 512     // oversubscribed; surplus blocks exit after registration

typedef __attribute__((ext_vector_type(4))) float f32x4;
typedef __attribute__((ext_vector_type(4))) int   i32x4;
typedef __attribute__((ext_vector_type(8))) __bf16 bf16x8;

__device__ __forceinline__ float sigf(float x) { return 1.f / (1.f + __expf(-x)); }
__device__ __forceinline__ float tanhf_fast(float x) { return 1.f - 2.f / (__expf(2.f * x) + 1.f); }

__device__ __forceinline__ unsigned short f2bf(float f) {
    union { __hip_bfloat16 h; unsigned short u; } cv;
    cv.h = __float2bfloat16(f);
    return cv.u;
}
__device__ __forceinline__ float bf2f(unsigned short u) {
    union { float f; unsigned v; } c; c.v = ((unsigned)u) << 16; return c.f;
}

// DPP quad_perm lane exchange (partners l^1,l^2,l^3 are within a quad): pure VALU, no LDS op.
#define QP(x, c) __int_as_float(__builtin_amdgcn_mov_dpp(__float_as_int(x), (c), 0xF, 0xF, true))
// ctrl: xor1 = [1,0,3,2] = 0xB1; xor2 = [2,3,0,1] = 0x4E; xor3 = [3,2,1,0] = 0x1B

// pack 4 unit-values (lanes n, n+4, n+8, n+12 of a 16-lane group) into u64 on lane n==0
__device__ __forceinline__ unsigned long long pack4(unsigned int h16) {
    unsigned int o4 = (unsigned int)__shfl_xor((int)h16, 4, 64);
    unsigned int p1 = h16 | (o4 << 16);
    unsigned int p2 = (unsigned int)__shfl_xor((int)p1, 8, 64);
    return (unsigned long long)p1 | ((unsigned long long)p2 << 32);
}

// L1-bypassing 16B load (fresh-address reads of L2 data within an XCD — r10-proven)
__device__ __forceinline__ bf16x8 load16_sc0(const unsigned short* p) {
    bf16x8 r;
    asm volatile("global_load_dwordx4 %0, %1, off sc0" : "=v"(r) : "v"(p));
    return r;
}

// ---- L3 flag barrier (r10-proven): agent-scope flags; ring data coherent via shared L2 ----
__device__ __forceinline__ void flag_arrive(unsigned* flags, int slot, unsigned target, int tid) {
    asm volatile("s_waitcnt vmcnt(0)" ::: "memory");   // ring stores completed (L2)
    __syncthreads();
    if (tid == 0)
        __hip_atomic_store(&flags[slot * 16], target, __ATOMIC_RELAXED, __HIP_MEMORY_SCOPE_AGENT);
}
__device__ __forceinline__ void flag_wait(unsigned* flags, unsigned target, int tid) {
    if (tid < NSLOT) {
        long sp = 0;
        while (__hip_atomic_load(&flags[tid * 16], __ATOMIC_RELAXED, __HIP_MEMORY_SCOPE_AGENT) < target) {
            if (++sp > (1L << 20)) break;              // safety valve
        }
    }
    __syncthreads();
    __builtin_amdgcn_sched_barrier(0);
    asm volatile("" ::: "memory");
}

// registration: read physical XCD id, claim a slot on it
__device__ __forceinline__ void register_block(unsigned* regcnt, int* s_slot, int* s_xcd, int tid) {
    if (tid == 0) {
        unsigned x;
        asm volatile("s_getreg_b32 %0, hwreg(HW_REG_XCC_ID)" : "=s"(x));
        x &= 7u;
        unsigned my = __hip_atomic_fetch_add(&regcnt[x * 16], 1u,
                                             __ATOMIC_RELAXED, __HIP_MEMORY_SCOPE_AGENT);
        *s_xcd = (int)x;
        *s_slot = (my < NSLOT) ? (int)my : -1;
    }
    __syncthreads();
}

// ---------------- init: zero control words with AGENT stores (L3) ----------------
// ctrl layout (dwords): regcnt_e[8*16] | regcnt_d[8*16] | gf_e[8*32*16] | gf_d[8*32*16]
#define CTRL_DWORDS (128 + 128 + 4096 + 4096)
__global__ void init_kernel(unsigned* ctrl) {
    int id = blockIdx.x * 256 + threadIdx.x;
    if (id < CTRL_DWORDS)
        __hip_atomic_store(&ctrl[id], 0u, __ATOMIC_RELAXED, __HIP_MEMORY_SCOPE_AGENT);
}

// ---------------- x (fp32 [B,T,D]) -> bf16 same layout ----------------
__global__ __launch_bounds__(256) void cvt_x(const float* __restrict__ x, unsigned short* __restrict__ xb) {
    int id = blockIdx.x * 256 + threadIdx.x;          // 524288
    if (id >= 524288) return;
    f32x4 v = *(const f32x4*)(x + (size_t)id * 4);
    ushort4 r;
    r.x = f2bf(v.x); r.y = f2bf(v.y); r.z = f2bf(v.z); r.w = f2bf(v.w);
    *(ushort4*)(xb + (size_t)id * 4) = r;
}

// ---------------- Wout fp32 -> bf16 (into the gxe region, dead after enc) ----------------
__global__ __launch_bounds__(256) void cvt_wout(const float* __restrict__ w, unsigned short* __restrict__ o) {
    int id = blockIdx.x * 256 + threadIdx.x;          // 4,096,000 x ushort4
    if (id >= 4096000) return;
    f32x4 v = *(const f32x4*)(w + (size_t)id * 4);
    ushort4 r;
    r.x = f2bf(v.x); r.y = f2bf(v.y); r.z = f2bf(v.z); r.w = f2bf(v.w);
    *(ushort4*)(o + (size_t)id * 4) = r;
}

// ---------------- gx GEMM: [4096,512](bf16) x [4096,512](fp32->bf16)^T -> bf16 [4096,4096] ----------------
__global__ __launch_bounds__(256) void gemm_gx(
        const unsigned short* __restrict__ A, const float* __restrict__ W,
        unsigned short* __restrict__ outb, int N) {
    __shared__ __align__(16) unsigned short lA[128 * 32];
    __shared__ __align__(16) unsigned short lB[128 * 32];
    const int tid = threadIdx.x, bid = blockIdx.x;
    const int mt = bid & 31, nt = bid >> 5;
    const int m0 = mt * 128, n0 = nt * 128;
    const int lane = tid & 63, wv = tid >> 6;
    const int wm = wv >> 1, wn = wv & 1;
    const int sr = tid >> 2, sc = (tid & 3) * 8;
    const int fr = lane & 15, kc = (lane >> 4) * 8;
    f32x4 acc[4][4];
    #pragma unroll
    for (int i = 0; i < 4; ++i)
        #pragma unroll
        for (int j = 0; j < 4; ++j) acc[i][j] = f32x4{0.f, 0.f, 0.f, 0.f};
    for (int k0 = 0; k0 < 512; k0 += 32) {
        __syncthreads();
        #pragma unroll
        for (int r0 = 0; r0 < 128; r0 += 64) {
            int r = sr + r0;
            *(i32x4*)(lA + r * 32 + sc) = *(const i32x4*)(A + (size_t)(m0 + r) * 512 + k0 + sc);
            f32x4 w0 = *(const f32x4*)(W + (size_t)(n0 + r) * 512 + k0 + sc);
            f32x4 w1 = *(const f32x4*)(W + (size_t)(n0 + r) * 512 + k0 + sc + 4);
            union { bf16x8 v; unsigned short u[8]; } cv;
            cv.u[0] = f2bf(w0.x); cv.u[1] = f2bf(w0.y); cv.u[2] = f2bf(w0.z); cv.u[3] = f2bf(w0.w);
            cv.u[4] = f2bf(w1.x); cv.u[5] = f2bf(w1.y); cv.u[6] = f2bf(w1.z); cv.u[7] = f2bf(w1.w);
            *(bf16x8*)(lB + r * 32 + sc) = cv.v;
        }
        __syncthreads();
        bf16x8 af[4], bfr[4];
        #pragma unroll
        for (int mi = 0; mi < 4; ++mi)
            af[mi] = *(const bf16x8*)(lA + (wm * 64 + mi * 16 + fr) * 32 + kc);
        #pragma unroll
        for (int ni = 0; ni < 4; ++ni)
            bfr[ni] = *(const bf16x8*)(lB + (wn * 64 + ni * 16 + fr) * 32 + kc);
        #pragma unroll
        for (int mi = 0; mi < 4; ++mi)
            #pragma unroll
            for (int ni = 0; ni < 4; ++ni)
                acc[mi][ni] = __builtin_amdgcn_mfma_f32_16x16x32_bf16(af[mi], bfr[ni], acc[mi][ni], 0, 0, 0);
    }
    const int orow = (lane >> 4) * 4;
    #pragma unroll
    for (int mi = 0; mi < 4; ++mi)
        #pragma unroll
        for (int ni = 0; ni < 4; ++ni) {
            int gm = m0 + wm * 64 + mi * 16 + orow;
            int gn = n0 + wn * 64 + ni * 16 + fr;
            #pragma unroll
            for (int j = 0; j < 4; ++j)
                outb[(size_t)(gm + j) * N + gn] = f2bf(acc[mi][ni][j]);
        }
}

// ---------------- encoder LSTM: XCD-group replicated, Whh in regs, gx hoisted, L2 rings ----------------
__global__ __launch_bounds__(256, 1) void enc_kernel(
        const float* __restrict__ Whh, const float* __restrict__ bih, const float* __restrict__ bhh,
        const unsigned short* __restrict__ gxe /*[4096][4096] bf16*/,
        unsigned short* ring_e, float* __restrict__ hT, unsigned* ctrl) {
    __shared__ int s_slot, s_xcd;
    const int tid = threadIdx.x;
    register_block(ctrl /*regcnt_e*/, &s_slot, &s_xcd, tid);
    const int slot = s_slot, xcd = s_xcd;
    if (slot < 0) return;
    unsigned* flags = ctrl + 256 + (size_t)xcd * NSLOT * 16;        // L3 flags (enc)
    unsigned short* ringg = ring_e + (size_t)xcd * 2 * 16384;

    const int l = tid & 63, wv = tid >> 6;
    const int n = l & 15;
    const int kch = (l >> 4) * 8;
    const int ub = slot * 32 + wv * 8;
    const int colA = (n & 3) * 1024 + ub + (n >> 2);
    const int colB = colA + 4;
    bf16x8 wA[32], wB[32];
    #pragma unroll
    for (int kk = 0; kk < 32; ++kk) {
        {
            const float* src = Whh + (size_t)colA * 1024 + kk * 32 + kch;
            f32x4 w0 = *(const f32x4*)src, w1 = *(const f32x4*)(src + 4);
            union { bf16x8 v; unsigned short u[8]; } cv;
            cv.u[0] = f2bf(w0.x); cv.u[1] = f2bf(w0.y); cv.u[2] = f2bf(w0.z); cv.u[3] = f2bf(w0.w);
            cv.u[4] = f2bf(w1.x); cv.u[5] = f2bf(w1.y); cv.u[6] = f2bf(w1.z); cv.u[7] = f2bf(w1.w);
            wA[kk] = cv.v;
        }
        {
            const float* src = Whh + (size_t)colB * 1024 + kk * 32 + kch;
            f32x4 w0 = *(const f32x4*)src, w1 = *(const f32x4*)(src + 4);
            union { bf16x8 v; unsigned short u[8]; } cv;
            cv.u[0] = f2bf(w0.x); cv.u[1] = f2bf(w0.y); cv.u[2] = f2bf(w0.z); cv.u[3] = f2bf(w0.w);
            cv.u[4] = f2bf(w1.x); cv.u[5] = f2bf(w1.y); cv.u[6] = f2bf(w1.z); cv.u[7] = f2bf(w1.w);
            wB[kk] = cv.v;
        }
    }
    const float biasA = bih[colA] + bhh[colA];
    const float biasB = bih[colB] + bhh[colB];
    float cA0 = 0.f, cA1 = 0.f, cA2 = 0.f, cA3 = 0.f;
    float cB0 = 0.f, cB1 = 0.f, cB2 = 0.f, cB3 = 0.f;
    const bool b0 = (l & 1), b1 = (l & 2);
    const bool g0lane = ((l & 3) == 0);
    const int batbase = (l >> 4) * 4;
    for (int t = 0; t < 256; ++t) {
        float gA0, gA1, gA2, gA3, gB0, gB1, gB2, gB3;
        {
            const unsigned short* g0p = gxe + ((size_t)(batbase + 0) * 256 + t) * 4096;
            const unsigned short* g1p = gxe + ((size_t)(batbase + 1) * 256 + t) * 4096;
            const unsigned short* g2p = gxe + ((size_t)(batbase + 2) * 256 + t) * 4096;
            const unsigned short* g3p = gxe + ((size_t)(batbase + 3) * 256 + t) * 4096;
            gA0 = bf2f(g0p[colA]); gB0 = bf2f(g0p[colB]);
            gA1 = bf2f(g1p[colA]); gB1 = bf2f(g1p[colB]);
            gA2 = bf2f(g2p[colA]); gB2 = bf2f(g2p[colB]);
            gA3 = bf2f(g3p[colA]); gB3 = bf2f(g3p[colB]);
        }
        f32x4 aA0 = {0.f,0.f,0.f,0.f}, aA1 = {0.f,0.f,0.f,0.f};
        f32x4 aB0 = {0.f,0.f,0.f,0.f}, aB1 = {0.f,0.f,0.f,0.f};
        if (t > 0) {
            flag_wait(flags, (unsigned)t, tid);
            const unsigned short* hb = ringg + ((t - 1) & 1) * 16384 + n * 32 + kch;
            bf16x8 ha[32];
            #pragma unroll
            for (int kk = 0; kk < 32; ++kk) ha[kk] = load16_sc0(hb + kk * 512);
            asm volatile("s_waitcnt vmcnt(0)" ::: "memory");   // single drain (was two)
            __builtin_amdgcn_sched_barrier(0);
            #pragma unroll
            for (int kk = 0; kk < 16; ++kk) {                  // 4 independent chains of 16
                aA0 = __builtin_amdgcn_mfma_f32_16x16x32_bf16(ha[kk],      wA[kk],      aA0, 0, 0, 0);
                aB0 = __builtin_amdgcn_mfma_f32_16x16x32_bf16(ha[kk],      wB[kk],      aB0, 0, 0, 0);
                aA1 = __builtin_amdgcn_mfma_f32_16x16x32_bf16(ha[kk + 16], wA[16 + kk], aA1, 0, 0, 0);
                aB1 = __builtin_amdgcn_mfma_f32_16x16x32_bf16(ha[kk + 16], wB[16 + kk], aB1, 0, 0, 0);
            }
        }
        unsigned short* sw = ringg + (t & 1) * 16384 + slot * 512 + wv * 8;
        #pragma unroll
        for (int j = 0; j < 4; ++j) {
            float gAj = (j == 0) ? gA0 : (j == 1) ? gA1 : (j == 2) ? gA2 : gA3;
            float gBj = (j == 0) ? gB0 : (j == 1) ? gB1 : (j == 2) ? gB2 : gB3;
            int bat = batbase + j;
            {
                float v = aA0[j] + aA1[j] + gAj + biasA;
                float vx1 = QP(v, 0xB1), vx2 = QP(v, 0x4E), vx3 = QP(v, 0x1B);
                float iv = b1 ? (b0 ? vx3 : vx2) : (b0 ? vx1 : v);
                float fv = b1 ? (b0 ? vx2 : vx3) : (b0 ? v   : vx1);
                float gv = b1 ? (b0 ? vx1 : v  ) : (b0 ? vx3 : vx2);
                float ov = b1 ? (b0 ? v   : vx1) : (b0 ? vx2 : vx3);
                float cj = (j == 0) ? cA0 : (j == 1) ? cA1 : (j == 2) ? cA2 : cA3;
                float cn = sigf(fv) * cj + sigf(iv) * tanhf_fast(gv);
                if (j == 0) cA0 = cn; else if (j == 1) cA1 = cn; else if (j == 2) cA2 = cn; else cA3 = cn;
                float h = sigf(ov) * tanhf_fast(cn);
                unsigned long long pk = pack4((unsigned)f2bf(h));
                if ((l & 15) == 0) *(unsigned long long*)(sw + bat * 32) = pk;        // plain -> L2
                if (g0lane && xcd == 0 && t == 255) hT[bat * 1024 + ub + (n >> 2)] = h;
            }
            {
                float v = aB0[j] + aB1[j] + gBj + biasB;
                float vx1 = QP(v, 0xB1), vx2 = QP(v, 0x4E), vx3 = QP(v, 0x1B);
                float iv = b1 ? (b0 ? vx3 : vx2) : (b0 ? vx1 : v);
                float fv = b1 ? (b0 ? vx2 : vx3) : (b0 ? v   : vx1);
                float gv = b1 ? (b0 ? vx1 : v  ) : (b0 ? vx3 : vx2);
                float ov = b1 ? (b0 ? v   : vx1) : (b0 ? vx2 : vx3);
                float cj = (j == 0) ? cB0 : (j == 1) ? cB1 : (j == 2) ? cB2 : cB3;
                float cn = sigf(fv) * cj + sigf(iv) * tanhf_fast(gv);
                if (j == 0) cB0 = cn; else if (j == 1) cB1 = cn; else if (j == 2) cB2 = cn; else cB3 = cn;
                float h = sigf(ov) * tanhf_fast(cn);
                unsigned long long pk = pack4((unsigned)f2bf(h));
                if ((l & 15) == 0) *(unsigned long long*)(sw + bat * 32 + 4) = pk;
                if (g0lane && xcd == 0 && t == 255) hT[bat * 1024 + ub + 4 + (n >> 2)] = h;
            }
        }
        flag_arrive(flags, slot, (unsigned)(t + 1), tid);
    }
}

// ---------------- mu / logvar / z ----------------
__global__ __launch_bounds__(256) void mlz_kernel(
        const float* __restrict__ hT, const float* __restrict__ Wmu, const float* __restrict__ bmu,
        const float* __restrict__ Wlv, const float* __restrict__ blv, const float* __restrict__ eps,
        unsigned short* __restrict__ z_ring, float* __restrict__ out_tail) {
    int id = blockIdx.x * 256 + threadIdx.x;   // 8192 = b*512 + l
    int l = id & 511, b = id >> 9;
    const float* hb = hT + b * 1024;
    const float* wm = Wmu + (size_t)l * 1024;
    const float* wl = Wlv + (size_t)l * 1024;
    float am = 0.f, al = 0.f;
    for (int k = 0; k < 256; ++k) {
        f32x4 h4 = *(const f32x4*)(hb + k * 4);
        f32x4 m4 = *(const f32x4*)(wm + k * 4);
        f32x4 l4 = *(const f32x4*)(wl + k * 4);
        am += m4.x * h4.x + m4.y * h4.y + m4.z * h4.z + m4.w * h4.w;
        al += l4.x * h4.x + l4.y * h4.y + l4.z * h4.z + l4.w * h4.w;
    }
    float mu = fmaxf(am + bmu[l], 0.f);
    float lv = fmaxf(al + blv[l], 0.f);
    float z  = eps[id] * __expf(0.5f * lv) + mu;
    z_ring[(l >> 4) * 256 + b * 16 + (l & 15)] = f2bf(z);   // dec ring layout
    out_tail[id] = z;
    out_tail[8192 + id] = mu;
    out_tail[16384 + id] = lv;
}

// ---------------- decoder LSTM: XCD-group replicated, inline x-MFMA, L2 rings ----------------
__global__ __launch_bounds__(256, 1) void dec_kernel(
        const float* __restrict__ Wih, const float* __restrict__ Whh,
        const float* __restrict__ bih, const float* __restrict__ bhh,
        const unsigned short* __restrict__ x_bf, const unsigned short* __restrict__ z_ring,
        unsigned short* ring_d, unsigned short* __restrict__ ys_bf, unsigned* ctrl) {
    __shared__ int s_slot, s_xcd;
    const int tid = threadIdx.x;
    register_block(ctrl + 128 /*regcnt_d*/, &s_slot, &s_xcd, tid);
    const int slot = s_slot, xcd = s_xcd;
    if (slot < 0) return;
    unsigned* flags = ctrl + 256 + 4096 + (size_t)xcd * NSLOT * 16;  // L3 flags (dec)
    unsigned short* ringg = ring_d + (size_t)xcd * 2 * 8192;

    const int l = tid & 63, wv = tid >> 6;
    const int n = l & 15;
    const int kch = (l >> 4) * 8;
    const int ub = slot * 16 + wv * 4;
    const int col = (n & 3) * 512 + ub + (n >> 2);
    bf16x8 wf[32];
    #pragma unroll
    for (int kk = 0; kk < 32; ++kk) {
        const float* src = (kk < 16) ? (Wih + (size_t)col * 512 + kk * 32 + kch)
                                     : (Whh + (size_t)col * 512 + (kk - 16) * 32 + kch);
        f32x4 w0 = *(const f32x4*)src, w1 = *(const f32x4*)(src + 4);
        union { bf16x8 v; unsigned short u[8]; } cv;
        cv.u[0] = f2bf(w0.x); cv.u[1] = f2bf(w0.y); cv.u[2] = f2bf(w0.z); cv.u[3] = f2bf(w0.w);
        cv.u[4] = f2bf(w1.x); cv.u[5] = f2bf(w1.y); cv.u[6] = f2bf(w1.z); cv.u[7] = f2bf(w1.w);
        wf[kk] = cv.v;
    }
    const float bias = bih[col] + bhh[col];
    float c0 = 0.f, c1 = 0.f, c2 = 0.f, c3 = 0.f;
    const bool b0 = (l & 1), b1 = (l & 2);
    const bool g0lane = ((l & 3) == 0);
    const int batbase = (l >> 4) * 4;
    for (int t = 0; t < 256; ++t) {
        f32x4 acc0 = {0.f,0.f,0.f,0.f}, acc1 = {0.f,0.f,0.f,0.f};
        if (t > 0) {                                    // x-part overlaps wait
            const unsigned short* xrow = x_bf + ((size_t)n * 256 + (t - 1)) * 512 + kch;
            #pragma unroll
            for (int kk = 0; kk < 16; ++kk) {
                bf16x8 a = *(const bf16x8*)(xrow + kk * 32);
                acc0 = __builtin_amdgcn_mfma_f32_16x16x32_bf16(a, wf[kk], acc0, 0, 0, 0);
            }
            flag_wait(flags, (unsigned)t, tid);
        }
        bf16x8 ha[16];
        if (t == 0) {
            #pragma unroll
            for (int kk = 0; kk < 16; ++kk) {
                int k = kk * 32 + kch;
                ha[kk] = *(const bf16x8*)(z_ring + (k >> 4) * 256 + n * 16 + (k & 15));
            }
        } else {
            const unsigned short* base = ringg + ((t - 1) & 1) * 8192;
            #pragma unroll
            for (int kk = 0; kk < 16; ++kk) {
                int k = kk * 32 + kch;
                ha[kk] = load16_sc0(base + (k >> 4) * 256 + n * 16 + (k & 15));
            }
            asm volatile("s_waitcnt vmcnt(0)" ::: "memory");
            __builtin_amdgcn_sched_barrier(0);
        }
        #pragma unroll
        for (int kk = 0; kk < 8; ++kk) {
            acc0 = __builtin_amdgcn_mfma_f32_16x16x32_bf16(ha[kk],     wf[16 + kk], acc0, 0, 0, 0);
            acc1 = __builtin_amdgcn_mfma_f32_16x16x32_bf16(ha[kk + 8], wf[24 + kk], acc1, 0, 0, 0);
        }
        unsigned short* sw = ringg + (t & 1) * 8192 + slot * 256 + wv * 4;
        #pragma unroll
        for (int j = 0; j < 4; ++j) {
            float v   = acc0[j] + acc1[j] + bias;
            float vx1 = QP(v, 0xB1), vx2 = QP(v, 0x4E), vx3 = QP(v, 0x1B);
            float iv = b1 ? (b0 ? vx3 : vx2) : (b0 ? vx1 : v);
            float fv = b1 ? (b0 ? vx2 : vx3) : (b0 ? v   : vx1);
            float gv = b1 ? (b0 ? vx1 : v  ) : (b0 ? vx3 : vx2);
            float ov = b1 ? (b0 ? v   : vx1) : (b0 ? vx2 : vx3);
            float cj = (j == 0) ? c0 : (j == 1) ? c1 : (j == 2) ? c2 : c3;
            float cn = sigf(fv) * cj + sigf(iv) * tanhf_fast(gv);
            if (j == 0) c0 = cn; else if (j == 1) c1 = cn; else if (j == 2) c2 = cn; else c3 = cn;
            float h = sigf(ov) * tanhf_fast(cn);
            unsigned long long pk = pack4((unsigned)f2bf(h));
            int bat = batbase + j;
            if ((l & 15) == 0) *(unsigned long long*)(sw + bat * 16) = pk;    // plain -> L2
            if (g0lane && xcd == 0)
                ys_bf[((size_t)bat * 256 + t) * 512 + ub + (n >> 2)] = f2bf(h);
        }
        flag_arrive(flags, slot, (unsigned)(t + 1), tid);
    }
}

// ---------------- logits GEMM: [4096,512]x[512,32000], BOTH operands bf16 (W pre-converted) ----------------
__global__ __launch_bounds__(256) void gemm_logits(
        const unsigned short* __restrict__ A, const unsigned short* __restrict__ Wb,
        const float* __restrict__ bout, float* __restrict__ out) {
    __shared__ __align__(16) unsigned short lA[128 * 32];
    __shared__ __align__(16) unsigned short lB[128 * 32];
    const int tid = threadIdx.x, bid = blockIdx.x;
    const int mt = bid & 31, nt = bid >> 5;           // m fastest: consecutive blocks share W-panel
    const int m0 = mt * 128, n0 = nt * 128;
    const int lane = tid & 63, wv = tid >> 6;
    const int wm = wv >> 1, wn = wv & 1;
    const int sr = tid >> 2, sc = (tid & 3) * 8;
    const int fr = lane & 15, kc = (lane >> 4) * 8;
    f32x4 acc[4][4];
    #pragma unroll
    for (int i = 0; i < 4; ++i)
        #pragma unroll
        for (int j = 0; j < 4; ++j) acc[i][j] = f32x4{0.f, 0.f, 0.f, 0.f};
    for (int k0 = 0; k0 < 512; k0 += 32) {
        __syncthreads();
        #pragma unroll
        for (int r0 = 0; r0 < 128; r0 += 64) {
            int r = sr + r0;
            *(i32x4*)(lA + r * 32 + sc) = *(const i32x4*)(A + (size_t)(m0 + r) * 512 + k0 + sc);
            *(i32x4*)(lB + r * 32 + sc) = *(const i32x4*)(Wb + (size_t)(n0 + r) * 512 + k0 + sc);
        }
        __syncthreads();
        bf16x8 af[4], bfr[4];
        #pragma unroll
        for (int mi = 0; mi < 4; ++mi)
            af[mi] = *(const bf16x8*)(lA + (wm * 64 + mi * 16 + fr) * 32 + kc);
        #pragma unroll
        for (int ni = 0; ni < 4; ++ni)
            bfr[ni] = *(const bf16x8*)(lB + (wn * 64 + ni * 16 + fr) * 32 + kc);
        #pragma unroll
        for (int mi = 0; mi < 4; ++mi)
            #pragma unroll
            for (int ni = 0; ni < 4; ++ni)
                acc[mi][ni] = __builtin_amdgcn_mfma_f32_16x16x32_bf16(af[mi], bfr[ni], acc[mi][ni], 0, 0, 0);
    }
    const int orow = (lane >> 4) * 4;
    #pragma unroll
    for (int mi = 0; mi < 4; ++mi)
        #pragma unroll
        for (int ni = 0; ni < 4; ++ni) {
            int gm = m0 + wm * 64 + mi * 16 + orow;
            int gn = n0 + wn * 64 + ni * 16 + fr;
            float bo = bout[gn];
            #pragma unroll
            for (int j = 0; j < 4; ++j)
                out[(size_t)(gm + j) * 32000 + gn] = acc[mi][ni][j] + bo;
        }
}

// ---------------- row softmax in-place (LDS row buffer: 1 read + 1 write of HBM) ----------------
__global__ __launch_bounds__(512) void softmax_kernel(float* __restrict__ out) {
    __shared__ __align__(16) float row[32000];
    __shared__ float red[8];
    const int tid = threadIdx.x;
    float* p = out + (size_t)blockIdx.x * 32000;
    float mx = -3.4e38f;
    for (int c = tid; c < 8000; c += 512) {
        f32x4 v = *(const f32x4*)(p + c * 4);
        *(f32x4*)(row + c * 4) = v;
        mx = fmaxf(mx, fmaxf(fmaxf(v.x, v.y), fmaxf(v.z, v.w)));
    }
    #pragma unroll
    for (int o = 32; o; o >>= 1) mx = fmaxf(mx, __shfl_xor(mx, o, 64));
    if ((tid & 63) == 0) red[tid >> 6] = mx;
    __syncthreads();
    if (tid == 0) {
        float m = red[0];
        for (int i = 1; i < 8; ++i) m = fmaxf(m, red[i]);
        red[0] = m;
    }
    __syncthreads();
    mx = red[0];
    __syncthreads();
    float s = 0.f;
    for (int c = tid; c < 8000; c += 512) {
        f32x4 v = *(f32x4*)(row + c * 4);
        v.x = __expf(v.x - mx); v.y = __expf(v.y - mx);
        v.z = __expf(v.z - mx); v.w = __expf(v.w - mx);
        *(f32x4*)(row + c * 4) = v;
        s += v.x + v.y + v.z + v.w;
    }
    #pragma unroll
    for (int o = 32; o; o >>= 1) s += __shfl_xor(s, o, 64);
    if ((tid & 63) == 0) red[tid >> 6] = s;
    __syncthreads();
    if (tid == 0) {
        float t2 = 0.f;
        for (int i = 0; i < 8; ++i) t2 += red[i];
        red[0] = t2;
    }
    __syncthreads();
    float inv = 1.f / red[0];
    for (int c = tid; c < 8000; c += 512) {
        f32x4 v = *(f32x4*)(row + c * 4);
        v.x *= inv; v.y *= inv; v.z *= inv; v.w *= inv;
        *(f32x4*)(p + c * 4) = v;
    }
}

extern "C" void kernel_launch(void* const* d_in, const int* in_sizes, int n_in,
                              void* d_out, int out_size, void* d_ws, size_t ws_size,
                              hipStream_t stream) {
    (void)in_sizes; (void)n_in; (void)out_size; (void)ws_size;
    const float* x    = (const float*)d_in[0];
    const float* eps  = (const float*)d_in[1];
    const float* eWih = (const float*)d_in[2];
    const float* eWhh = (const float*)d_in[3];
    const float* ebih = (const float*)d_in[4];
    const float* ebhh = (const float*)d_in[5];
    const float* Wmu  = (const float*)d_in[6];
    const float* bmu  = (const float*)d_in[7];
    const float* Wlv  = (const float*)d_in[8];
    const float* blv  = (const float*)d_in[9];
    const float* dWih = (const float*)d_in[10];
    const float* dWhh = (const float*)d_in[11];
    const float* dbih = (const float*)d_in[12];
    const float* dbhh = (const float*)d_in[13];
    const float* Wout = (const float*)d_in[14];
    const float* bout = (const float*)d_in[15];
    float* out = (float*)d_out;

    // workspace layout (~42 MB)
    char* ws = (char*)d_ws;
    unsigned* ctrl         = (unsigned*)ws;                         // 64 KB reserved (init-zeroed)
    unsigned short* x_bf   = (unsigned short*)(ws + 65536);         // 4 MB
    unsigned short* ysbf   = x_bf + (size_t)16 * 256 * 512;         // 4 MB
    unsigned short* ring_e = ysbf + (size_t)4096 * 512;             // 512 KB
    unsigned short* ring_d = ring_e + (size_t)8 * 2 * 16384;        // 256 KB
    unsigned short* z_ring = ring_d + (size_t)8 * 2 * 8192;         // 16 KB
    float* hT              = (float*)(z_ring + 8192);               // 64 KB
    unsigned short* gxe    = (unsigned short*)(hT + 16384);         // 33.5 MB (gxe; reused as wo_bf after enc)
    unsigned short* wo_bf  = gxe;                                   // 32000*512*2 = 32.8 MB

    hipLaunchKernelGGL(init_kernel, dim3(33), dim3(256), 0, stream, ctrl);
    hipLaunchKernelGGL(cvt_x, dim3(2048), dim3(256), 0, stream, x, x_bf);
    hipLaunchKernelGGL(gemm_gx, dim3(1024), dim3(256), 0, stream, x_bf, eWih, gxe, 4096);
    hipLaunchKernelGGL(enc_kernel, dim3(GRID_LSTM), dim3(256), 0, stream,
                       eWhh, ebih, ebhh, gxe, ring_e, hT, ctrl);
    hipLaunchKernelGGL(cvt_wout, dim3(16000), dim3(256), 0, stream, Wout, wo_bf);   // gxe dead after enc
    hipLaunchKernelGGL(mlz_kernel, dim3(32), dim3(256), 0, stream,
                       hT, Wmu, bmu, Wlv, blv, eps, z_ring, out + 131072000);
    hipLaunchKernelGGL(dec_kernel, dim3(GRID_LSTM), dim3(256), 0, stream,
                       dWih, dWhh, dbih, dbhh, x_bf, z_ring, ring_d, ysbf, ctrl);
    hipLaunchKernelGGL(gemm_logits, dim3(8000), dim3(256), 0, stream, ysbf, wo_bf, bout, out);
    hipLaunchKernelGGL(softmax_kernel, dim3(4096), dim3(512), 0, stream, out);
}

// Round 15
// 3506.818 us; speedup vs baseline: 1.1471x; 1.0104x over previous
//
#include <hip/hip_runtime.h>
#include <hip/hip_bf16.h>
#include <stdint.h>

// Problem dims (fixed): B=16, T=256, D=512, H=1024, L=512, V=32000
#define NSLOT 32          // workers per XCD group
#define GRID_LSTM 512     // oversubscribed; surplus blocks exit after registration

typedef __attribute__((ext_vector_type(4))) float f32x4;
typedef __attribute__((ext_vector_type(4))) int   i32x4;
typedef __attribute__((ext_vector_type(8))) __bf16 bf16x8;

__device__ __forceinline__ float sigf(float x) { return 1.f / (1.f + __expf(-x)); }
__device__ __forceinline__ float tanhf_fast(float x) { return 1.f - 2.f / (__expf(2.f * x) + 1.f); }

__device__ __forceinline__ unsigned short f2bf(float f) {
    union { __hip_bfloat16 h; unsigned short u; } cv;
    cv.h = __float2bfloat16(f);
    return cv.u;
}
__device__ __forceinline__ float bf2f(unsigned short u) {
    union { float f; unsigned v; } c; c.v = ((unsigned)u) << 16; return c.f;
}

// DPP quad_perm lane exchange (partners l^1,l^2,l^3 are within a quad): pure VALU, no LDS op.
#define QP(x, c) __int_as_float(__builtin_amdgcn_mov_dpp(__float_as_int(x), (c), 0xF, 0xF, true))
// ctrl: xor1 = [1,0,3,2] = 0xB1; xor2 = [2,3,0,1] = 0x4E; xor3 = [3,2,1,0] = 0x1B

// pack 4 unit-values (lanes n, n+4, n+8, n+12 of a 16-lane group) into u64 on lane n==0
__device__ __forceinline__ unsigned long long pack4(unsigned int h16) {
    unsigned int o4 = (unsigned int)__shfl_xor((int)h16, 4, 64);
    unsigned int p1 = h16 | (o4 << 16);
    unsigned int p2 = (unsigned int)__shfl_xor((int)p1, 8, 64);
    return (unsigned long long)p1 | ((unsigned long long)p2 << 32);
}

// L1-bypassing 16B load (fresh-address reads of L2 data within an XCD — r10-proven)
__device__ __forceinline__ bf16x8 load16_sc0(const unsigned short* p) {
    bf16x8 r;
    asm volatile("global_load_dwordx4 %0, %1, off sc0" : "=v"(r) : "v"(p));
    return r;
}

// async global->LDS DMA, 16 B/lane: lane i lands at lds_base + i*16 (wave-uniform base)
__device__ __forceinline__ void gld_lds16(const unsigned short* g, unsigned short* l) {
    __builtin_amdgcn_global_load_lds(
        (const __attribute__((address_space(1))) unsigned int*)g,
        (__attribute__((address_space(3))) unsigned int*)l, 16, 0, 0);
}

// ---- L3 flag barrier (r10-proven): agent-scope flags; ring data coherent via shared L2 ----
__device__ __forceinline__ void flag_arrive(unsigned* flags, int slot, unsigned target, int tid) {
    asm volatile("s_waitcnt vmcnt(0)" ::: "memory");   // ring stores completed (L2)
    __syncthreads();
    if (tid == 0)
        __hip_atomic_store(&flags[slot * 16], target, __ATOMIC_RELAXED, __HIP_MEMORY_SCOPE_AGENT);
}
__device__ __forceinline__ void flag_wait(unsigned* flags, unsigned target, int tid) {
    if (tid < NSLOT) {
        long sp = 0;
        while (__hip_atomic_load(&flags[tid * 16], __ATOMIC_RELAXED, __HIP_MEMORY_SCOPE_AGENT) < target) {
            if (++sp > (1L << 20)) break;              // safety valve
        }
    }
    __syncthreads();
    __builtin_amdgcn_sched_barrier(0);
    asm volatile("" ::: "memory");
}

// registration: read physical XCD id, claim a slot on it
__device__ __forceinline__ void register_block(unsigned* regcnt, int* s_slot, int* s_xcd, int tid) {
    if (tid == 0) {
        unsigned x;
        asm volatile("s_getreg_b32 %0, hwreg(HW_REG_XCC_ID)" : "=s"(x));
        x &= 7u;
        unsigned my = __hip_atomic_fetch_add(&regcnt[x * 16], 1u,
                                             __ATOMIC_RELAXED, __HIP_MEMORY_SCOPE_AGENT);
        *s_xcd = (int)x;
        *s_slot = (my < NSLOT) ? (int)my : -1;
    }
    __syncthreads();
}

// ---------------- init: zero control words with AGENT stores (L3) ----------------
#define CTRL_DWORDS (128 + 128 + 4096 + 4096)
__global__ void init_kernel(unsigned* ctrl) {
    int id = blockIdx.x * 256 + threadIdx.x;
    if (id < CTRL_DWORDS)
        __hip_atomic_store(&ctrl[id], 0u, __ATOMIC_RELAXED, __HIP_MEMORY_SCOPE_AGENT);
}

// ---------------- generic fp32 -> bf16 (x, eWih, Wout) ----------------
__global__ __launch_bounds__(256) void cvt_f32_bf16(const float* __restrict__ w,
                                                    unsigned short* __restrict__ o, int n4) {
    int id = blockIdx.x * 256 + threadIdx.x;
    if (id >= n4) return;
    f32x4 v = *(const f32x4*)(w + (size_t)id * 4);
    ushort4 r;
    r.x = f2bf(v.x); r.y = f2bf(v.y); r.z = f2bf(v.z); r.w = f2bf(v.w);
    *(ushort4*)(o + (size_t)id * 4) = r;
}

// ---------------- gx GEMM: bf16 x bf16^T -> bf16 [4096,N], global_load_lds staging ----------------
__global__ __launch_bounds__(256) void gemm_gx(
        const unsigned short* __restrict__ A, const unsigned short* __restrict__ Bm,
        unsigned short* __restrict__ outb, int N) {
    __shared__ __align__(16) unsigned short lA[128 * 32];
    __shared__ __align__(16) unsigned short lB[128 * 32];
    const int tid = threadIdx.x, bid = blockIdx.x;
    const int mt = bid & 31, nt = bid >> 5;
    const int m0 = mt * 128, n0 = nt * 128;
    const int lane = tid & 63, wvv = tid >> 6;
    const int wm = wvv >> 1, wn = wvv & 1;
    const int sr = tid >> 2, sc = (tid & 3) * 8;
    const int fr = lane & 15, kc = (lane >> 4) * 8;
    unsigned short* ldsA0 = lA + wvv * 512;            // wave-uniform LDS bases (byte = wvv*1024)
    unsigned short* ldsA1 = lA + 2048 + wvv * 512;
    unsigned short* ldsB0 = lB + wvv * 512;
    unsigned short* ldsB1 = lB + 2048 + wvv * 512;
    f32x4 acc[4][4];
    #pragma unroll
    for (int i = 0; i < 4; ++i)
        #pragma unroll
        for (int j = 0; j < 4; ++j) acc[i][j] = f32x4{0.f, 0.f, 0.f, 0.f};
    for (int k0 = 0; k0 < 512; k0 += 32) {
        __syncthreads();
        gld_lds16(A  + (size_t)(m0 + sr) * 512 + k0 + sc,        ldsA0);
        gld_lds16(A  + (size_t)(m0 + sr + 64) * 512 + k0 + sc,   ldsA1);
        gld_lds16(Bm + (size_t)(n0 + sr) * 512 + k0 + sc,        ldsB0);
        gld_lds16(Bm + (size_t)(n0 + sr + 64) * 512 + k0 + sc,   ldsB1);
        __syncthreads();
        bf16x8 af[4], bfr[4];
        #pragma unroll
        for (int mi = 0; mi < 4; ++mi)
            af[mi] = *(const bf16x8*)(lA + (wm * 64 + mi * 16 + fr) * 32 + kc);
        #pragma unroll
        for (int ni = 0; ni < 4; ++ni)
            bfr[ni] = *(const bf16x8*)(lB + (wn * 64 + ni * 16 + fr) * 32 + kc);
        #pragma unroll
        for (int mi = 0; mi < 4; ++mi)
            #pragma unroll
            for (int ni = 0; ni < 4; ++ni)
                acc[mi][ni] = __builtin_amdgcn_mfma_f32_16x16x32_bf16(af[mi], bfr[ni], acc[mi][ni], 0, 0, 0);
    }
    const int orow = (lane >> 4) * 4;
    #pragma unroll
    for (int mi = 0; mi < 4; ++mi)
        #pragma unroll
        for (int ni = 0; ni < 4; ++ni) {
            int gm = m0 + wm * 64 + mi * 16 + orow;
            int gn = n0 + wn * 64 + ni * 16 + fr;
            #pragma unroll
            for (int j = 0; j < 4; ++j)
                outb[(size_t)(gm + j) * N + gn] = f2bf(acc[mi][ni][j]);
        }
}

// ---------------- encoder LSTM: XCD-group replicated, Whh in regs, gx hoisted, L2 rings ----------------
__global__ __launch_bounds__(256, 1) void enc_kernel(
        const float* __restrict__ Whh, const float* __restrict__ bih, const float* __restrict__ bhh,
        const unsigned short* __restrict__ gxe /*[4096][4096] bf16*/,
        unsigned short* ring_e, float* __restrict__ hT, unsigned* ctrl) {
    __shared__ int s_slot, s_xcd;
    const int tid = threadIdx.x;
    register_block(ctrl /*regcnt_e*/, &s_slot, &s_xcd, tid);
    const int slot = s_slot, xcd = s_xcd;
    if (slot < 0) return;
    unsigned* flags = ctrl + 256 + (size_t)xcd * NSLOT * 16;        // L3 flags (enc)
    unsigned short* ringg = ring_e + (size_t)xcd * 2 * 16384;

    const int l = tid & 63, wv = tid >> 6;
    const int n = l & 15;
    const int kch = (l >> 4) * 8;
    const int ub = slot * 32 + wv * 8;
    const int colA = (n & 3) * 1024 + ub + (n >> 2);
    const int colB = colA + 4;
    bf16x8 wA[32], wB[32];
    #pragma unroll
    for (int kk = 0; kk < 32; ++kk) {
        {
            const float* src = Whh + (size_t)colA * 1024 + kk * 32 + kch;
            f32x4 w0 = *(const f32x4*)src, w1 = *(const f32x4*)(src + 4);
            union { bf16x8 v; unsigned short u[8]; } cv;
            cv.u[0] = f2bf(w0.x); cv.u[1] = f2bf(w0.y); cv.u[2] = f2bf(w0.z); cv.u[3] = f2bf(w0.w);
            cv.u[4] = f2bf(w1.x); cv.u[5] = f2bf(w1.y); cv.u[6] = f2bf(w1.z); cv.u[7] = f2bf(w1.w);
            wA[kk] = cv.v;
        }
        {
            const float* src = Whh + (size_t)colB * 1024 + kk * 32 + kch;
            f32x4 w0 = *(const f32x4*)src, w1 = *(const f32x4*)(src + 4);
            union { bf16x8 v; unsigned short u[8]; } cv;
            cv.u[0] = f2bf(w0.x); cv.u[1] = f2bf(w0.y); cv.u[2] = f2bf(w0.z); cv.u[3] = f2bf(w0.w);
            cv.u[4] = f2bf(w1.x); cv.u[5] = f2bf(w1.y); cv.u[6] = f2bf(w1.z); cv.u[7] = f2bf(w1.w);
            wB[kk] = cv.v;
        }
    }
    const float biasA = bih[colA] + bhh[colA];
    const float biasB = bih[colB] + bhh[colB];
    float cA0 = 0.f, cA1 = 0.f, cA2 = 0.f, cA3 = 0.f;
    float cB0 = 0.f, cB1 = 0.f, cB2 = 0.f, cB3 = 0.f;
    const bool b0 = (l & 1), b1 = (l & 2);
    const bool g0lane = ((l & 3) == 0);
    const int batbase = (l >> 4) * 4;
    for (int t = 0; t < 256; ++t) {
        float gA0, gA1, gA2, gA3, gB0, gB1, gB2, gB3;
        {
            const unsigned short* g0p = gxe + ((size_t)(batbase + 0) * 256 + t) * 4096;
            const unsigned short* g1p = gxe + ((size_t)(batbase + 1) * 256 + t) * 4096;
            const unsigned short* g2p = gxe + ((size_t)(batbase + 2) * 256 + t) * 4096;
            const unsigned short* g3p = gxe + ((size_t)(batbase + 3) * 256 + t) * 4096;
            gA0 = bf2f(g0p[colA]); gB0 = bf2f(g0p[colB]);
            gA1 = bf2f(g1p[colA]); gB1 = bf2f(g1p[colB]);
            gA2 = bf2f(g2p[colA]); gB2 = bf2f(g2p[colB]);
            gA3 = bf2f(g3p[colA]); gB3 = bf2f(g3p[colB]);
        }
        f32x4 aA0 = {0.f,0.f,0.f,0.f}, aA1 = {0.f,0.f,0.f,0.f};
        f32x4 aB0 = {0.f,0.f,0.f,0.f}, aB1 = {0.f,0.f,0.f,0.f};
        if (t > 0) {
            flag_wait(flags, (unsigned)t, tid);
            const unsigned short* hb = ringg + ((t - 1) & 1) * 16384 + n * 32 + kch;
            bf16x8 ha[32];
            #pragma unroll
            for (int kk = 0; kk < 32; ++kk) ha[kk] = load16_sc0(hb + kk * 512);
            asm volatile("s_waitcnt vmcnt(0)" ::: "memory");   // single drain
            __builtin_amdgcn_sched_barrier(0);
            #pragma unroll
            for (int kk = 0; kk < 16; ++kk) {                  // 4 independent chains of 16
                aA0 = __builtin_amdgcn_mfma_f32_16x16x32_bf16(ha[kk],      wA[kk],      aA0, 0, 0, 0);
                aB0 = __builtin_amdgcn_mfma_f32_16x16x32_bf16(ha[kk],      wB[kk],      aB0, 0, 0, 0);
                aA1 = __builtin_amdgcn_mfma_f32_16x16x32_bf16(ha[kk + 16], wA[16 + kk], aA1, 0, 0, 0);
                aB1 = __builtin_amdgcn_mfma_f32_16x16x32_bf16(ha[kk + 16], wB[16 + kk], aB1, 0, 0, 0);
            }
        }
        unsigned short* sw = ringg + (t & 1) * 16384 + slot * 512 + wv * 8;
        #pragma unroll
        for (int j = 0; j < 4; ++j) {
            float gAj = (j == 0) ? gA0 : (j == 1) ? gA1 : (j == 2) ? gA2 : gA3;
            float gBj = (j == 0) ? gB0 : (j == 1) ? gB1 : (j == 2) ? gB2 : gB3;
            int bat = batbase + j;
            {
                float v = aA0[j] + aA1[j] + gAj + biasA;
                float vx1 = QP(v, 0xB1), vx2 = QP(v, 0x4E), vx3 = QP(v, 0x1B);
                float iv = b1 ? (b0 ? vx3 : vx2) : (b0 ? vx1 : v);
                float fv = b1 ? (b0 ? vx2 : vx3) : (b0 ? v   : vx1);
                float gv = b1 ? (b0 ? vx1 : v  ) : (b0 ? vx3 : vx2);
                float ov = b1 ? (b0 ? v   : vx1) : (b0 ? vx2 : vx3);
                float cj = (j == 0) ? cA0 : (j == 1) ? cA1 : (j == 2) ? cA2 : cA3;
                float cn = sigf(fv) * cj + sigf(iv) * tanhf_fast(gv);
                if (j == 0) cA0 = cn; else if (j == 1) cA1 = cn; else if (j == 2) cA2 = cn; else cA3 = cn;
                float h = sigf(ov) * tanhf_fast(cn);
                unsigned long long pk = pack4((unsigned)f2bf(h));
                if ((l & 15) == 0) *(unsigned long long*)(sw + bat * 32) = pk;        // plain -> L2
                if (g0lane && xcd == 0 && t == 255) hT[bat * 1024 + ub + (n >> 2)] = h;
            }
            {
                float v = aB0[j] + aB1[j] + gBj + biasB;
                float vx1 = QP(v, 0xB1), vx2 = QP(v, 0x4E), vx3 = QP(v, 0x1B);
                float iv = b1 ? (b0 ? vx3 : vx2) : (b0 ? vx1 : v);
                float fv = b1 ? (b0 ? vx2 : vx3) : (b0 ? v   : vx1);
                float gv = b1 ? (b0 ? vx1 : v  ) : (b0 ? vx3 : vx2);
                float ov = b1 ? (b0 ? v   : vx1) : (b0 ? vx2 : vx3);
                float cj = (j == 0) ? cB0 : (j == 1) ? cB1 : (j == 2) ? cB2 : cB3;
                float cn = sigf(fv) * cj + sigf(iv) * tanhf_fast(gv);
                if (j == 0) cB0 = cn; else if (j == 1) cB1 = cn; else if (j == 2) cB2 = cn; else cB3 = cn;
                float h = sigf(ov) * tanhf_fast(cn);
                unsigned long long pk = pack4((unsigned)f2bf(h));
                if ((l & 15) == 0) *(unsigned long long*)(sw + bat * 32 + 4) = pk;
                if (g0lane && xcd == 0 && t == 255) hT[bat * 1024 + ub + 4 + (n >> 2)] = h;
            }
        }
        flag_arrive(flags, slot, (unsigned)(t + 1), tid);
    }
}

// ---------------- mu / logvar / z ----------------
__global__ __launch_bounds__(256) void mlz_kernel(
        const float* __restrict__ hT, const float* __restrict__ Wmu, const float* __restrict__ bmu,
        const float* __restrict__ Wlv, const float* __restrict__ blv, const float* __restrict__ eps,
        unsigned short* __restrict__ z_ring, float* __restrict__ out_tail) {
    int id = blockIdx.x * 256 + threadIdx.x;   // 8192 = b*512 + l
    int l = id & 511, b = id >> 9;
    const float* hb = hT + b * 1024;
    const float* wm = Wmu + (size_t)l * 1024;
    const float* wl = Wlv + (size_t)l * 1024;
    float am = 0.f, al = 0.f;
    for (int k = 0; k < 256; ++k) {
        f32x4 h4 = *(const f32x4*)(hb + k * 4);
        f32x4 m4 = *(const f32x4*)(wm + k * 4);
        f32x4 l4 = *(const f32x4*)(wl + k * 4);
        am += m4.x * h4.x + m4.y * h4.y + m4.z * h4.z + m4.w * h4.w;
        al += l4.x * h4.x + l4.y * h4.y + l4.z * h4.z + l4.w * h4.w;
    }
    float mu = fmaxf(am + bmu[l], 0.f);
    float lv = fmaxf(al + blv[l], 0.f);
    float z  = eps[id] * __expf(0.5f * lv) + mu;
    z_ring[(l >> 4) * 256 + b * 16 + (l & 15)] = f2bf(z);   // dec ring layout
    out_tail[id] = z;
    out_tail[8192 + id] = mu;
    out_tail[16384 + id] = lv;
}

// ---------------- decoder LSTM: XCD-group replicated, inline x-MFMA, L2 rings ----------------
__global__ __launch_bounds__(256, 1) void dec_kernel(
        const float* __restrict__ Wih, const float* __restrict__ Whh,
        const float* __restrict__ bih, const float* __restrict__ bhh,
        const unsigned short* __restrict__ x_bf, const unsigned short* __restrict__ z_ring,
        unsigned short* ring_d, unsigned short* __restrict__ ys_bf, unsigned* ctrl) {
    __shared__ int s_slot, s_xcd;
    const int tid = threadIdx.x;
    register_block(ctrl + 128 /*regcnt_d*/, &s_slot, &s_xcd, tid);
    const int slot = s_slot, xcd = s_xcd;
    if (slot < 0) return;
    unsigned* flags = ctrl + 256 + 4096 + (size_t)xcd * NSLOT * 16;  // L3 flags (dec)
    unsigned short* ringg = ring_d + (size_t)xcd * 2 * 8192;

    const int l = tid & 63, wv = tid >> 6;
    const int n = l & 15;
    const int kch = (l >> 4) * 8;
    const int ub = slot * 16 + wv * 4;
    const int col = (n & 3) * 512 + ub + (n >> 2);
    bf16x8 wf[32];
    #pragma unroll
    for (int kk = 0; kk < 32; ++kk) {
        const float* src = (kk < 16) ? (Wih + (size_t)col * 512 + kk * 32 + kch)
                                     : (Whh + (size_t)col * 512 + (kk - 16) * 32 + kch);
        f32x4 w0 = *(const f32x4*)src, w1 = *(const f32x4*)(src + 4);
        union { bf16x8 v; unsigned short u[8]; } cv;
        cv.u[0] = f2bf(w0.x); cv.u[1] = f2bf(w0.y); cv.u[2] = f2bf(w0.z); cv.u[3] = f2bf(w0.w);
        cv.u[4] = f2bf(w1.x); cv.u[5] = f2bf(w1.y); cv.u[6] = f2bf(w1.z); cv.u[7] = f2bf(w1.w);
        wf[kk] = cv.v;
    }
    const float bias = bih[col] + bhh[col];
    float c0 = 0.f, c1 = 0.f, c2 = 0.f, c3 = 0.f;
    const bool b0 = (l & 1), b1 = (l & 2);
    const bool g0lane = ((l & 3) == 0);
    const int batbase = (l >> 4) * 4;
    for (int t = 0; t < 256; ++t) {
        f32x4 acc0 = {0.f,0.f,0.f,0.f}, acc1 = {0.f,0.f,0.f,0.f};
        if (t > 0) {                                    // x-part overlaps wait
            const unsigned short* xrow = x_bf + ((size_t)n * 256 + (t - 1)) * 512 + kch;
            #pragma unroll
            for (int kk = 0; kk < 16; ++kk) {
                bf16x8 a = *(const bf16x8*)(xrow + kk * 32);
                acc0 = __builtin_amdgcn_mfma_f32_16x16x32_bf16(a, wf[kk], acc0, 0, 0, 0);
            }
            flag_wait(flags, (unsigned)t, tid);
        }
        bf16x8 ha[16];
        if (t == 0) {
            #pragma unroll
            for (int kk = 0; kk < 16; ++kk) {
                int k = kk * 32 + kch;
                ha[kk] = *(const bf16x8*)(z_ring + (k >> 4) * 256 + n * 16 + (k & 15));
            }
        } else {
            const unsigned short* base = ringg + ((t - 1) & 1) * 8192;
            #pragma unroll
            for (int kk = 0; kk < 16; ++kk) {
                int k = kk * 32 + kch;
                ha[kk] = load16_sc0(base + (k >> 4) * 256 + n * 16 + (k & 15));
            }
            asm volatile("s_waitcnt vmcnt(0)" ::: "memory");
            __builtin_amdgcn_sched_barrier(0);
        }
        #pragma unroll
        for (int kk = 0; kk < 8; ++kk) {
            acc0 = __builtin_amdgcn_mfma_f32_16x16x32_bf16(ha[kk],     wf[16 + kk], acc0, 0, 0, 0);
            acc1 = __builtin_amdgcn_mfma_f32_16x16x32_bf16(ha[kk + 8], wf[24 + kk], acc1, 0, 0, 0);
        }
        unsigned short* sw = ringg + (t & 1) * 8192 + slot * 256 + wv * 4;
        #pragma unroll
        for (int j = 0; j < 4; ++j) {
            float v   = acc0[j] + acc1[j] + bias;
            float vx1 = QP(v, 0xB1), vx2 = QP(v, 0x4E), vx3 = QP(v, 0x1B);
            float iv = b1 ? (b0 ? vx3 : vx2) : (b0 ? vx1 : v);
            float fv = b1 ? (b0 ? vx2 : vx3) : (b0 ? v   : vx1);
            float gv = b1 ? (b0 ? vx1 : v  ) : (b0 ? vx3 : vx2);
            float ov = b1 ? (b0 ? v   : vx1) : (b0 ? vx2 : vx3);
            float cj = (j == 0) ? c0 : (j == 1) ? c1 : (j == 2) ? c2 : c3;
            float cn = sigf(fv) * cj + sigf(iv) * tanhf_fast(gv);
            if (j == 0) c0 = cn; else if (j == 1) c1 = cn; else if (j == 2) c2 = cn; else c3 = cn;
            float h = sigf(ov) * tanhf_fast(cn);
            unsigned long long pk = pack4((unsigned)f2bf(h));
            int bat = batbase + j;
            if ((l & 15) == 0) *(unsigned long long*)(sw + bat * 16) = pk;    // plain -> L2
            if (g0lane && xcd == 0)
                ys_bf[((size_t)bat * 256 + t) * 512 + ub + (n >> 2)] = f2bf(h);
        }
        flag_arrive(flags, slot, (unsigned)(t + 1), tid);
    }
}

// ---------------- logits GEMM: bf16 x bf16, global_load_lds staging, f32+bias out ----------------
__global__ __launch_bounds__(256) void gemm_logits(
        const unsigned short* __restrict__ A, const unsigned short* __restrict__ Wb,
        const float* __restrict__ bout, float* __restrict__ out) {
    __shared__ __align__(16) unsigned short lA[128 * 32];
    __shared__ __align__(16) unsigned short lB[128 * 32];
    const int tid = threadIdx.x, bid = blockIdx.x;
    const int mt = bid & 31, nt = bid >> 5;           // m fastest: consecutive blocks share W-panel
    const int m0 = mt * 128, n0 = nt * 128;
    const int lane = tid & 63, wvv = tid >> 6;
    const int wm = wvv >> 1, wn = wvv & 1;
    const int sr = tid >> 2, sc = (tid & 3) * 8;
    const int fr = lane & 15, kc = (lane >> 4) * 8;
    unsigned short* ldsA0 = lA + wvv * 512;
    unsigned short* ldsA1 = lA + 2048 + wvv * 512;
    unsigned short* ldsB0 = lB + wvv * 512;
    unsigned short* ldsB1 = lB + 2048 + wvv * 512;
    f32x4 acc[4][4];
    #pragma unroll
    for (int i = 0; i < 4; ++i)
        #pragma unroll
        for (int j = 0; j < 4; ++j) acc[i][j] = f32x4{0.f, 0.f, 0.f, 0.f};
    for (int k0 = 0; k0 < 512; k0 += 32) {
        __syncthreads();
        gld_lds16(A  + (size_t)(m0 + sr) * 512 + k0 + sc,        ldsA0);
        gld_lds16(A  + (size_t)(m0 + sr + 64) * 512 + k0 + sc,   ldsA1);
        gld_lds16(Wb + (size_t)(n0 + sr) * 512 + k0 + sc,        ldsB0);
        gld_lds16(Wb + (size_t)(n0 + sr + 64) * 512 + k0 + sc,   ldsB1);
        __syncthreads();
        bf16x8 af[4], bfr[4];
        #pragma unroll
        for (int mi = 0; mi < 4; ++mi)
            af[mi] = *(const bf16x8*)(lA + (wm * 64 + mi * 16 + fr) * 32 + kc);
        #pragma unroll
        for (int ni = 0; ni < 4; ++ni)
            bfr[ni] = *(const bf16x8*)(lB + (wn * 64 + ni * 16 + fr) * 32 + kc);
        #pragma unroll
        for (int mi = 0; mi < 4; ++mi)
            #pragma unroll
            for (int ni = 0; ni < 4; ++ni)
                acc[mi][ni] = __builtin_amdgcn_mfma_f32_16x16x32_bf16(af[mi], bfr[ni], acc[mi][ni], 0, 0, 0);
    }
    const int orow = (lane >> 4) * 4;
    #pragma unroll
    for (int mi = 0; mi < 4; ++mi)
        #pragma unroll
        for (int ni = 0; ni < 4; ++ni) {
            int gm = m0 + wm * 64 + mi * 16 + orow;
            int gn = n0 + wn * 64 + ni * 16 + fr;
            float bo = bout[gn];
            #pragma unroll
            for (int j = 0; j < 4; ++j)
                out[(size_t)(gm + j) * 32000 + gn] = acc[mi][ni][j] + bo;
        }
}

// ---------------- row softmax in-place (LDS row buffer: 1 read + 1 write of HBM) ----------------
__global__ __launch_bounds__(512) void softmax_kernel(float* __restrict__ out) {
    __shared__ __align__(16) float row[32000];
    __shared__ float red[8];
    const int tid = threadIdx.x;
    float* p = out + (size_t)blockIdx.x * 32000;
    float mx = -3.4e38f;
    for (int c = tid; c < 8000; c += 512) {
        f32x4 v = *(const f32x4*)(p + c * 4);
        *(f32x4*)(row + c * 4) = v;
        mx = fmaxf(mx, fmaxf(fmaxf(v.x, v.y), fmaxf(v.z, v.w)));
    }
    #pragma unroll
    for (int o = 32; o; o >>= 1) mx = fmaxf(mx, __shfl_xor(mx, o, 64));
    if ((tid & 63) == 0) red[tid >> 6] = mx;
    __syncthreads();
    if (tid == 0) {
        float m = red[0];
        for (int i = 1; i < 8; ++i) m = fmaxf(m, red[i]);
        red[0] = m;
    }
    __syncthreads();
    mx = red[0];
    __syncthreads();
    float s = 0.f;
    for (int c = tid; c < 8000; c += 512) {
        f32x4 v = *(f32x4*)(row + c * 4);
        v.x = __expf(v.x - mx); v.y = __expf(v.y - mx);
        v.z = __expf(v.z - mx); v.w = __expf(v.w - mx);
        *(f32x4*)(row + c * 4) = v;
        s += v.x + v.y + v.z + v.w;
    }
    #pragma unroll
    for (int o = 32; o; o >>= 1) s += __shfl_xor(s, o, 64);
    if ((tid & 63) == 0) red[tid >> 6] = s;
    __syncthreads();
    if (tid == 0) {
        float t2 = 0.f;
        for (int i = 0; i < 8; ++i) t2 += red[i];
        red[0] = t2;
    }
    __syncthreads();
    float inv = 1.f / red[0];
    for (int c = tid; c < 8000; c += 512) {
        f32x4 v = *(f32x4*)(row + c * 4);
        v.x *= inv; v.y *= inv; v.z *= inv; v.w *= inv;
        *(f32x4*)(p + c * 4) = v;
    }
}

extern "C" void kernel_launch(void* const* d_in, const int* in_sizes, int n_in,
                              void* d_out, int out_size, void* d_ws, size_t ws_size,
                              hipStream_t stream) {
    (void)in_sizes; (void)n_in; (void)out_size; (void)ws_size;
    const float* x    = (const float*)d_in[0];
    const float* eps  = (const float*)d_in[1];
    const float* eWih = (const float*)d_in[2];
    const float* eWhh = (const float*)d_in[3];
    const float* ebih = (const float*)d_in[4];
    const float* ebhh = (const float*)d_in[5];
    const float* Wmu  = (const float*)d_in[6];
    const float* bmu  = (const float*)d_in[7];
    const float* Wlv  = (const float*)d_in[8];
    const float* blv  = (const float*)d_in[9];
    const float* dWih = (const float*)d_in[10];
    const float* dWhh = (const float*)d_in[11];
    const float* dbih = (const float*)d_in[12];
    const float* dbhh = (const float*)d_in[13];
    const float* Wout = (const float*)d_in[14];
    const float* bout = (const float*)d_in[15];
    float* out = (float*)d_out;

    // workspace layout (~42 MB)
    char* ws = (char*)d_ws;
    unsigned* ctrl         = (unsigned*)ws;                         // 64 KB reserved (init-zeroed)
    unsigned short* x_bf   = (unsigned short*)(ws + 65536);         // 4 MB
    unsigned short* ysbf   = x_bf + (size_t)16 * 256 * 512;         // 4 MB (wih_bf before dec)
    unsigned short* ring_e = ysbf + (size_t)4096 * 512;             // 512 KB
    unsigned short* ring_d = ring_e + (size_t)8 * 2 * 16384;        // 256 KB
    unsigned short* z_ring = ring_d + (size_t)8 * 2 * 8192;         // 16 KB
    float* hT              = (float*)(z_ring + 8192);               // 64 KB
    unsigned short* gxe    = (unsigned short*)(hT + 16384);         // 33.5 MB (gxe; reused as wo_bf)
    unsigned short* wih_bf = ysbf;                                  // eWih bf16 (dead once dec starts)
    unsigned short* wo_bf  = gxe;                                   // Wout bf16 (after enc)

    hipLaunchKernelGGL(init_kernel, dim3(33), dim3(256), 0, stream, ctrl);
    hipLaunchKernelGGL(cvt_f32_bf16, dim3(2048), dim3(256), 0, stream, x, x_bf, 524288);
    hipLaunchKernelGGL(cvt_f32_bf16, dim3(2048), dim3(256), 0, stream, eWih, wih_bf, 524288);
    hipLaunchKernelGGL(gemm_gx, dim3(1024), dim3(256), 0, stream, x_bf, wih_bf, gxe, 4096);
    hipLaunchKernelGGL(enc_kernel, dim3(GRID_LSTM), dim3(256), 0, stream,
                       eWhh, ebih, ebhh, gxe, ring_e, hT, ctrl);
    hipLaunchKernelGGL(cvt_f32_bf16, dim3(16000), dim3(256), 0, stream, Wout, wo_bf, 4096000);
    hipLaunchKernelGGL(mlz_kernel, dim3(32), dim3(256), 0, stream,
                       hT, Wmu, bmu, Wlv, blv, eps, z_ring, out + 131072000);
    hipLaunchKernelGGL(dec_kernel, dim3(GRID_LSTM), dim3(256), 0, stream,
                       dWih, dWhh, dbih, dbhh, x_bf, z_ring, ring_d, ysbf, ctrl);
    hipLaunchKernelGGL(gemm_logits, dim3(8000), dim3(256), 0, stream, ysbf, wo_bf, bout, out);
    hipLaunchKernelGGL(softmax_kernel, dim3(4096), dim3(512), 0, stream, out);
}

// Round 16
// 3403.508 us; speedup vs baseline: 1.1820x; 1.0304x over previous
//
#include <hip/hip_runtime.h>
#include <hip/hip_bf16.h>
#include <stdint.h>

// Problem dims (fixed): B=16, T=256, D=512, H=1024, L=512, V=32000
#define NSLOT 32          // workers per XCD group
#define GRID_LSTM 512     // oversubscribed; surplus blocks exit after registration

typedef __attribute__((ext_vector_type(4))) float f32x4;
typedef __attribute__((ext_vector_type(4))) int   i32x4;
typedef __attribute__((ext_vector_type(8))) __bf16 bf16x8;
typedef __attribute__((ext_vector_type(8))) unsigned short u16x8;

__device__ __forceinline__ float sigf(float x) { return 1.f / (1.f + __expf(-x)); }
__device__ __forceinline__ float tanhf_fast(float x) { return 1.f - 2.f / (__expf(2.f * x) + 1.f); }

__device__ __forceinline__ unsigned short f2bf(float f) {
    union { __hip_bfloat16 h; unsigned short u; } cv;
    cv.h = __float2bfloat16(f);
    return cv.u;
}
__device__ __forceinline__ float bf2f(unsigned short u) {
    union { float f; unsigned v; } c; c.v = ((unsigned)u) << 16; return c.f;
}

// DPP quad_perm lane exchange (partners l^1,l^2,l^3 are within a quad): pure VALU, no LDS op.
#define QP(x, c) __int_as_float(__builtin_amdgcn_mov_dpp(__float_as_int(x), (c), 0xF, 0xF, true))
// ctrl: xor1 = [1,0,3,2] = 0xB1; xor2 = [2,3,0,1] = 0x4E; xor3 = [3,2,1,0] = 0x1B

// pack 4 unit-values (lanes n, n+4, n+8, n+12 of a 16-lane group) into u64 on lane n==0
__device__ __forceinline__ unsigned long long pack4(unsigned int h16) {
    unsigned int o4 = (unsigned int)__shfl_xor((int)h16, 4, 64);
    unsigned int p1 = h16 | (o4 << 16);
    unsigned int p2 = (unsigned int)__shfl_xor((int)p1, 8, 64);
    return (unsigned long long)p1 | ((unsigned long long)p2 << 32);
}

// L1-bypassing 16B load (fresh-address reads of L2 data within an XCD — r10-proven)
__device__ __forceinline__ bf16x8 load16_sc0(const unsigned short* p) {
    bf16x8 r;
    asm volatile("global_load_dwordx4 %0, %1, off sc0" : "=v"(r) : "v"(p));
    return r;
}

// async global->LDS DMA, 16 B/lane: lane i lands at lds_base + i*16 (wave-uniform base)
__device__ __forceinline__ void gld_lds16(const unsigned short* g, unsigned short* l) {
    __builtin_amdgcn_global_load_lds(
        (const __attribute__((address_space(1))) unsigned int*)g,
        (__attribute__((address_space(3))) unsigned int*)l, 16, 0, 0);
}

// ---- L3 flag barrier (r10-proven): agent-scope flags; ring data coherent via shared L2 ----
__device__ __forceinline__ void flag_arrive(unsigned* flags, int slot, unsigned target, int tid) {
    asm volatile("s_waitcnt vmcnt(0)" ::: "memory");   // ring stores completed (L2)
    __syncthreads();
    if (tid == 0)
        __hip_atomic_store(&flags[slot * 16], target, __ATOMIC_RELAXED, __HIP_MEMORY_SCOPE_AGENT);
}
__device__ __forceinline__ void flag_wait(unsigned* flags, unsigned target, int tid) {
    if (tid < NSLOT) {
        long sp = 0;
        while (__hip_atomic_load(&flags[tid * 16], __ATOMIC_RELAXED, __HIP_MEMORY_SCOPE_AGENT) < target) {
            if (++sp > (1L << 20)) break;              // safety valve
        }
    }
    __syncthreads();
    __builtin_amdgcn_sched_barrier(0);
    asm volatile("" ::: "memory");
}

// registration: read physical XCD id, claim a slot on it
__device__ __forceinline__ void register_block(unsigned* regcnt, int* s_slot, int* s_xcd, int tid) {
    if (tid == 0) {
        unsigned x;
        asm volatile("s_getreg_b32 %0, hwreg(HW_REG_XCC_ID)" : "=s"(x));
        x &= 7u;
        unsigned my = __hip_atomic_fetch_add(&regcnt[x * 16], 1u,
                                             __ATOMIC_RELAXED, __HIP_MEMORY_SCOPE_AGENT);
        *s_xcd = (int)x;
        *s_slot = (my < NSLOT) ? (int)my : -1;
    }
    __syncthreads();
}

// ---------------- init: zero control words with AGENT stores (L3) ----------------
#define CTRL_DWORDS (128 + 128 + 4096 + 4096)
__global__ void init_kernel(unsigned* ctrl) {
    int id = blockIdx.x * 256 + threadIdx.x;
    if (id < CTRL_DWORDS)
        __hip_atomic_store(&ctrl[id], 0u, __ATOMIC_RELAXED, __HIP_MEMORY_SCOPE_AGENT);
}

// ---------------- generic fp32 -> bf16 (x, eWih, Wout) ----------------
__global__ __launch_bounds__(256) void cvt_f32_bf16(const float* __restrict__ w,
                                                    unsigned short* __restrict__ o, int n4) {
    int id = blockIdx.x * 256 + threadIdx.x;
    if (id >= n4) return;
    f32x4 v = *(const f32x4*)(w + (size_t)id * 4);
    ushort4 r;
    r.x = f2bf(v.x); r.y = f2bf(v.y); r.z = f2bf(v.z); r.w = f2bf(v.w);
    *(ushort4*)(o + (size_t)id * 4) = r;
}

// ---------------- gx GEMM: bf16 x bf16^T -> bf16 [4096,N], global_load_lds staging ----------------
__global__ __launch_bounds__(256) void gemm_gx(
        const unsigned short* __restrict__ A, const unsigned short* __restrict__ Bm,
        unsigned short* __restrict__ outb, int N) {
    __shared__ __align__(16) unsigned short lA[128 * 32];
    __shared__ __align__(16) unsigned short lB[128 * 32];
    const int tid = threadIdx.x, bid = blockIdx.x;
    const int mt = bid & 31, nt = bid >> 5;
    const int m0 = mt * 128, n0 = nt * 128;
    const int lane = tid & 63, wvv = tid >> 6;
    const int wm = wvv >> 1, wn = wvv & 1;
    const int sr = tid >> 2, sc = (tid & 3) * 8;
    const int fr = lane & 15, kc = (lane >> 4) * 8;
    unsigned short* ldsA0 = lA + wvv * 512;            // wave-uniform LDS bases (byte = wvv*1024)
    unsigned short* ldsA1 = lA + 2048 + wvv * 512;
    unsigned short* ldsB0 = lB + wvv * 512;
    unsigned short* ldsB1 = lB + 2048 + wvv * 512;
    f32x4 acc[4][4];
    #pragma unroll
    for (int i = 0; i < 4; ++i)
        #pragma unroll
        for (int j = 0; j < 4; ++j) acc[i][j] = f32x4{0.f, 0.f, 0.f, 0.f};
    for (int k0 = 0; k0 < 512; k0 += 32) {
        __syncthreads();
        gld_lds16(A  + (size_t)(m0 + sr) * 512 + k0 + sc,        ldsA0);
        gld_lds16(A  + (size_t)(m0 + sr + 64) * 512 + k0 + sc,   ldsA1);
        gld_lds16(Bm + (size_t)(n0 + sr) * 512 + k0 + sc,        ldsB0);
        gld_lds16(Bm + (size_t)(n0 + sr + 64) * 512 + k0 + sc,   ldsB1);
        __syncthreads();
        bf16x8 af[4], bfr[4];
        #pragma unroll
        for (int mi = 0; mi < 4; ++mi)
            af[mi] = *(const bf16x8*)(lA + (wm * 64 + mi * 16 + fr) * 32 + kc);
        #pragma unroll
        for (int ni = 0; ni < 4; ++ni)
            bfr[ni] = *(const bf16x8*)(lB + (wn * 64 + ni * 16 + fr) * 32 + kc);
        #pragma unroll
        for (int mi = 0; mi < 4; ++mi)
            #pragma unroll
            for (int ni = 0; ni < 4; ++ni)
                acc[mi][ni] = __builtin_amdgcn_mfma_f32_16x16x32_bf16(af[mi], bfr[ni], acc[mi][ni], 0, 0, 0);
    }
    const int orow = (lane >> 4) * 4;
    #pragma unroll
    for (int mi = 0; mi < 4; ++mi)
        #pragma unroll
        for (int ni = 0; ni < 4; ++ni) {
            int gm = m0 + wm * 64 + mi * 16 + orow;
            int gn = n0 + wn * 64 + ni * 16 + fr;
            #pragma unroll
            for (int j = 0; j < 4; ++j)
                outb[(size_t)(gm + j) * N + gn] = f2bf(acc[mi][ni][j]);
        }
}

// ---------------- encoder LSTM: XCD-group replicated, Whh in regs, gx hoisted, L2 rings ----------------
__global__ __launch_bounds__(256, 1) void enc_kernel(
        const float* __restrict__ Whh, const float* __restrict__ bih, const float* __restrict__ bhh,
        const unsigned short* __restrict__ gxe /*[4096][4096] bf16*/,
        unsigned short* ring_e, float* __restrict__ hT, unsigned* ctrl) {
    __shared__ int s_slot, s_xcd;
    const int tid = threadIdx.x;
    register_block(ctrl /*regcnt_e*/, &s_slot, &s_xcd, tid);
    const int slot = s_slot, xcd = s_xcd;
    if (slot < 0) return;
    unsigned* flags = ctrl + 256 + (size_t)xcd * NSLOT * 16;        // L3 flags (enc)
    unsigned short* ringg = ring_e + (size_t)xcd * 2 * 16384;

    const int l = tid & 63, wv = tid >> 6;
    const int n = l & 15;
    const int kch = (l >> 4) * 8;
    const int ub = slot * 32 + wv * 8;
    const int colA = (n & 3) * 1024 + ub + (n >> 2);
    const int colB = colA + 4;
    bf16x8 wA[32], wB[32];
    #pragma unroll
    for (int kk = 0; kk < 32; ++kk) {
        {
            const float* src = Whh + (size_t)colA * 1024 + kk * 32 + kch;
            f32x4 w0 = *(const f32x4*)src, w1 = *(const f32x4*)(src + 4);
            union { bf16x8 v; unsigned short u[8]; } cv;
            cv.u[0] = f2bf(w0.x); cv.u[1] = f2bf(w0.y); cv.u[2] = f2bf(w0.z); cv.u[3] = f2bf(w0.w);
            cv.u[4] = f2bf(w1.x); cv.u[5] = f2bf(w1.y); cv.u[6] = f2bf(w1.z); cv.u[7] = f2bf(w1.w);
            wA[kk] = cv.v;
        }
        {
            const float* src = Whh + (size_t)colB * 1024 + kk * 32 + kch;
            f32x4 w0 = *(const f32x4*)src, w1 = *(const f32x4*)(src + 4);
            union { bf16x8 v; unsigned short u[8]; } cv;
            cv.u[0] = f2bf(w0.x); cv.u[1] = f2bf(w0.y); cv.u[2] = f2bf(w0.z); cv.u[3] = f2bf(w0.w);
            cv.u[4] = f2bf(w1.x); cv.u[5] = f2bf(w1.y); cv.u[6] = f2bf(w1.z); cv.u[7] = f2bf(w1.w);
            wB[kk] = cv.v;
        }
    }
    const float biasA = bih[colA] + bhh[colA];
    const float biasB = bih[colB] + bhh[colB];
    float cA0 = 0.f, cA1 = 0.f, cA2 = 0.f, cA3 = 0.f;
    float cB0 = 0.f, cB1 = 0.f, cB2 = 0.f, cB3 = 0.f;
    const bool b0 = (l & 1), b1 = (l & 2);
    const bool g0lane = ((l & 3) == 0);
    const int batbase = (l >> 4) * 4;
    for (int t = 0; t < 256; ++t) {
        float gA0, gA1, gA2, gA3, gB0, gB1, gB2, gB3;
        {
            const unsigned short* g0p = gxe + ((size_t)(batbase + 0) * 256 + t) * 4096;
            const unsigned short* g1p = gxe + ((size_t)(batbase + 1) * 256 + t) * 4096;
            const unsigned short* g2p = gxe + ((size_t)(batbase + 2) * 256 + t) * 4096;
            const unsigned short* g3p = gxe + ((size_t)(batbase + 3) * 256 + t) * 4096;
            gA0 = bf2f(g0p[colA]); gB0 = bf2f(g0p[colB]);
            gA1 = bf2f(g1p[colA]); gB1 = bf2f(g1p[colB]);
            gA2 = bf2f(g2p[colA]); gB2 = bf2f(g2p[colB]);
            gA3 = bf2f(g3p[colA]); gB3 = bf2f(g3p[colB]);
        }
        f32x4 aA0 = {0.f,0.f,0.f,0.f}, aA1 = {0.f,0.f,0.f,0.f};
        f32x4 aB0 = {0.f,0.f,0.f,0.f}, aB1 = {0.f,0.f,0.f,0.f};
        if (t > 0) {
            flag_wait(flags, (unsigned)t, tid);
            const unsigned short* hb = ringg + ((t - 1) & 1) * 16384 + n * 32 + kch;
            bf16x8 ha[32];
            #pragma unroll
            for (int kk = 0; kk < 32; ++kk) ha[kk] = load16_sc0(hb + kk * 512);
            asm volatile("s_waitcnt vmcnt(0)" ::: "memory");   // single drain
            __builtin_amdgcn_sched_barrier(0);
            #pragma unroll
            for (int kk = 0; kk < 16; ++kk) {                  // 4 independent chains of 16
                aA0 = __builtin_amdgcn_mfma_f32_16x16x32_bf16(ha[kk],      wA[kk],      aA0, 0, 0, 0);
                aB0 = __builtin_amdgcn_mfma_f32_16x16x32_bf16(ha[kk],      wB[kk],      aB0, 0, 0, 0);
                aA1 = __builtin_amdgcn_mfma_f32_16x16x32_bf16(ha[kk + 16], wA[16 + kk], aA1, 0, 0, 0);
                aB1 = __builtin_amdgcn_mfma_f32_16x16x32_bf16(ha[kk + 16], wB[16 + kk], aB1, 0, 0, 0);
            }
        }
        unsigned short* sw = ringg + (t & 1) * 16384 + slot * 512 + wv * 8;
        #pragma unroll
        for (int j = 0; j < 4; ++j) {
            float gAj = (j == 0) ? gA0 : (j == 1) ? gA1 : (j == 2) ? gA2 : gA3;
            float gBj = (j == 0) ? gB0 : (j == 1) ? gB1 : (j == 2) ? gB2 : gB3;
            int bat = batbase + j;
            {
                float v = aA0[j] + aA1[j] + gAj + biasA;
                float vx1 = QP(v, 0xB1), vx2 = QP(v, 0x4E), vx3 = QP(v, 0x1B);
                float iv = b1 ? (b0 ? vx3 : vx2) : (b0 ? vx1 : v);
                float fv = b1 ? (b0 ? vx2 : vx3) : (b0 ? v   : vx1);
                float gv = b1 ? (b0 ? vx1 : v  ) : (b0 ? vx3 : vx2);
                float ov = b1 ? (b0 ? v   : vx1) : (b0 ? vx2 : vx3);
                float cj = (j == 0) ? cA0 : (j == 1) ? cA1 : (j == 2) ? cA2 : cA3;
                float cn = sigf(fv) * cj + sigf(iv) * tanhf_fast(gv);
                if (j == 0) cA0 = cn; else if (j == 1) cA1 = cn; else if (j == 2) cA2 = cn; else cA3 = cn;
                float h = sigf(ov) * tanhf_fast(cn);
                unsigned long long pk = pack4((unsigned)f2bf(h));
                if ((l & 15) == 0) *(unsigned long long*)(sw + bat * 32) = pk;        // plain -> L2
                if (g0lane && xcd == 0 && t == 255) hT[bat * 1024 + ub + (n >> 2)] = h;
            }
            {
                float v = aB0[j] + aB1[j] + gBj + biasB;
                float vx1 = QP(v, 0xB1), vx2 = QP(v, 0x4E), vx3 = QP(v, 0x1B);
                float iv = b1 ? (b0 ? vx3 : vx2) : (b0 ? vx1 : v);
                float fv = b1 ? (b0 ? vx2 : vx3) : (b0 ? v   : vx1);
                float gv = b1 ? (b0 ? vx1 : v  ) : (b0 ? vx3 : vx2);
                float ov = b1 ? (b0 ? v   : vx1) : (b0 ? vx2 : vx3);
                float cj = (j == 0) ? cB0 : (j == 1) ? cB1 : (j == 2) ? cB2 : cB3;
                float cn = sigf(fv) * cj + sigf(iv) * tanhf_fast(gv);
                if (j == 0) cB0 = cn; else if (j == 1) cB1 = cn; else if (j == 2) cB2 = cn; else cB3 = cn;
                float h = sigf(ov) * tanhf_fast(cn);
                unsigned long long pk = pack4((unsigned)f2bf(h));
                if ((l & 15) == 0) *(unsigned long long*)(sw + bat * 32 + 4) = pk;
                if (g0lane && xcd == 0 && t == 255) hT[bat * 1024 + ub + 4 + (n >> 2)] = h;
            }
        }
        flag_arrive(flags, slot, (unsigned)(t + 1), tid);
    }
}

// ---------------- mu / logvar / z ----------------
__global__ __launch_bounds__(256) void mlz_kernel(
        const float* __restrict__ hT, const float* __restrict__ Wmu, const float* __restrict__ bmu,
        const float* __restrict__ Wlv, const float* __restrict__ blv, const float* __restrict__ eps,
        unsigned short* __restrict__ z_ring, float* __restrict__ out_tail) {
    int id = blockIdx.x * 256 + threadIdx.x;   // 8192 = b*512 + l
    int l = id & 511, b = id >> 9;
    const float* hb = hT + b * 1024;
    const float* wm = Wmu + (size_t)l * 1024;
    const float* wl = Wlv + (size_t)l * 1024;
    float am = 0.f, al = 0.f;
    for (int k = 0; k < 256; ++k) {
        f32x4 h4 = *(const f32x4*)(hb + k * 4);
        f32x4 m4 = *(const f32x4*)(wm + k * 4);
        f32x4 l4 = *(const f32x4*)(wl + k * 4);
        am += m4.x * h4.x + m4.y * h4.y + m4.z * h4.z + m4.w * h4.w;
        al += l4.x * h4.x + l4.y * h4.y + l4.z * h4.z + l4.w * h4.w;
    }
    float mu = fmaxf(am + bmu[l], 0.f);
    float lv = fmaxf(al + blv[l], 0.f);
    float z  = eps[id] * __expf(0.5f * lv) + mu;
    z_ring[(l >> 4) * 256 + b * 16 + (l & 15)] = f2bf(z);   // dec ring layout
    out_tail[id] = z;
    out_tail[8192 + id] = mu;
    out_tail[16384 + id] = lv;
}

// ---------------- decoder LSTM: XCD-group replicated, inline x-MFMA, L2 rings ----------------
__global__ __launch_bounds__(256, 1) void dec_kernel(
        const float* __restrict__ Wih, const float* __restrict__ Whh,
        const float* __restrict__ bih, const float* __restrict__ bhh,
        const unsigned short* __restrict__ x_bf, const unsigned short* __restrict__ z_ring,
        unsigned short* ring_d, unsigned short* __restrict__ ys_bf, unsigned* ctrl) {
    __shared__ int s_slot, s_xcd;
    const int tid = threadIdx.x;
    register_block(ctrl + 128 /*regcnt_d*/, &s_slot, &s_xcd, tid);
    const int slot = s_slot, xcd = s_xcd;
    if (slot < 0) return;
    unsigned* flags = ctrl + 256 + 4096 + (size_t)xcd * NSLOT * 16;  // L3 flags (dec)
    unsigned short* ringg = ring_d + (size_t)xcd * 2 * 8192;

    const int l = tid & 63, wv = tid >> 6;
    const int n = l & 15;
    const int kch = (l >> 4) * 8;
    const int ub = slot * 16 + wv * 4;
    const int col = (n & 3) * 512 + ub + (n >> 2);
    bf16x8 wf[32];
    #pragma unroll
    for (int kk = 0; kk < 32; ++kk) {
        const float* src = (kk < 16) ? (Wih + (size_t)col * 512 + kk * 32 + kch)
                                     : (Whh + (size_t)col * 512 + (kk - 16) * 32 + kch);
        f32x4 w0 = *(const f32x4*)src, w1 = *(const f32x4*)(src + 4);
        union { bf16x8 v; unsigned short u[8]; } cv;
        cv.u[0] = f2bf(w0.x); cv.u[1] = f2bf(w0.y); cv.u[2] = f2bf(w0.z); cv.u[3] = f2bf(w0.w);
        cv.u[4] = f2bf(w1.x); cv.u[5] = f2bf(w1.y); cv.u[6] = f2bf(w1.z); cv.u[7] = f2bf(w1.w);
        wf[kk] = cv.v;
    }
    const float bias = bih[col] + bhh[col];
    float c0 = 0.f, c1 = 0.f, c2 = 0.f, c3 = 0.f;
    const bool b0 = (l & 1), b1 = (l & 2);
    const bool g0lane = ((l & 3) == 0);
    const int batbase = (l >> 4) * 4;
    for (int t = 0; t < 256; ++t) {
        f32x4 acc0 = {0.f,0.f,0.f,0.f}, acc1 = {0.f,0.f,0.f,0.f};
        if (t > 0) {                                    // x-part overlaps wait
            const unsigned short* xrow = x_bf + ((size_t)n * 256 + (t - 1)) * 512 + kch;
            #pragma unroll
            for (int kk = 0; kk < 16; ++kk) {
                bf16x8 a = *(const bf16x8*)(xrow + kk * 32);
                acc0 = __builtin_amdgcn_mfma_f32_16x16x32_bf16(a, wf[kk], acc0, 0, 0, 0);
            }
            flag_wait(flags, (unsigned)t, tid);
        }
        bf16x8 ha[16];
        if (t == 0) {
            #pragma unroll
            for (int kk = 0; kk < 16; ++kk) {
                int k = kk * 32 + kch;
                ha[kk] = *(const bf16x8*)(z_ring + (k >> 4) * 256 + n * 16 + (k & 15));
            }
        } else {
            const unsigned short* base = ringg + ((t - 1) & 1) * 8192;
            #pragma unroll
            for (int kk = 0; kk < 16; ++kk) {
                int k = kk * 32 + kch;
                ha[kk] = load16_sc0(base + (k >> 4) * 256 + n * 16 + (k & 15));
            }
            asm volatile("s_waitcnt vmcnt(0)" ::: "memory");
            __builtin_amdgcn_sched_barrier(0);
        }
        #pragma unroll
        for (int kk = 0; kk < 8; ++kk) {
            acc0 = __builtin_amdgcn_mfma_f32_16x16x32_bf16(ha[kk],     wf[16 + kk], acc0, 0, 0, 0);
            acc1 = __builtin_amdgcn_mfma_f32_16x16x32_bf16(ha[kk + 8], wf[24 + kk], acc1, 0, 0, 0);
        }
        unsigned short* sw = ringg + (t & 1) * 8192 + slot * 256 + wv * 4;
        #pragma unroll
        for (int j = 0; j < 4; ++j) {
            float v   = acc0[j] + acc1[j] + bias;
            float vx1 = QP(v, 0xB1), vx2 = QP(v, 0x4E), vx3 = QP(v, 0x1B);
            float iv = b1 ? (b0 ? vx3 : vx2) : (b0 ? vx1 : v);
            float fv = b1 ? (b0 ? vx2 : vx3) : (b0 ? v   : vx1);
            float gv = b1 ? (b0 ? vx1 : v  ) : (b0 ? vx3 : vx2);
            float ov = b1 ? (b0 ? v   : vx1) : (b0 ? vx2 : vx3);
            float cj = (j == 0) ? c0 : (j == 1) ? c1 : (j == 2) ? c2 : c3;
            float cn = sigf(fv) * cj + sigf(iv) * tanhf_fast(gv);
            if (j == 0) c0 = cn; else if (j == 1) c1 = cn; else if (j == 2) c2 = cn; else c3 = cn;
            float h = sigf(ov) * tanhf_fast(cn);
            unsigned long long pk = pack4((unsigned)f2bf(h));
            int bat = batbase + j;
            if ((l & 15) == 0) *(unsigned long long*)(sw + bat * 16) = pk;    // plain -> L2
            if (g0lane && xcd == 0)
                ys_bf[((size_t)bat * 256 + t) * 512 + ub + (n >> 2)] = f2bf(h);
        }
        flag_arrive(flags, slot, (unsigned)(t + 1), tid);
    }
}

// ---------------- logits GEMM: bf16 x bf16, gld_lds staging; f32 out OR bf16 intermediate ----------------
__global__ __launch_bounds__(256) void gemm_logits(
        const unsigned short* __restrict__ A, const unsigned short* __restrict__ Wb,
        const float* __restrict__ bout, float* __restrict__ out,
        unsigned short* __restrict__ lgbf, int bfmode) {
    __shared__ __align__(16) unsigned short lA[128 * 32];
    __shared__ __align__(16) unsigned short lB[128 * 32];
    const int tid = threadIdx.x, bid = blockIdx.x;
    const int mt = bid & 31, nt = bid >> 5;           // m fastest: consecutive blocks share W-panel
    const int m0 = mt * 128, n0 = nt * 128;
    const int lane = tid & 63, wvv = tid >> 6;
    const int wm = wvv >> 1, wn = wvv & 1;
    const int sr = tid >> 2, sc = (tid & 3) * 8;
    const int fr = lane & 15, kc = (lane >> 4) * 8;
    unsigned short* ldsA0 = lA + wvv * 512;
    unsigned short* ldsA1 = lA + 2048 + wvv * 512;
    unsigned short* ldsB0 = lB + wvv * 512;
    unsigned short* ldsB1 = lB + 2048 + wvv * 512;
    f32x4 acc[4][4];
    #pragma unroll
    for (int i = 0; i < 4; ++i)
        #pragma unroll
        for (int j = 0; j < 4; ++j) acc[i][j] = f32x4{0.f, 0.f, 0.f, 0.f};
    for (int k0 = 0; k0 < 512; k0 += 32) {
        __syncthreads();
        gld_lds16(A  + (size_t)(m0 + sr) * 512 + k0 + sc,        ldsA0);
        gld_lds16(A  + (size_t)(m0 + sr + 64) * 512 + k0 + sc,   ldsA1);
        gld_lds16(Wb + (size_t)(n0 + sr) * 512 + k0 + sc,        ldsB0);
        gld_lds16(Wb + (size_t)(n0 + sr + 64) * 512 + k0 + sc,   ldsB1);
        __syncthreads();
        bf16x8 af[4], bfr[4];
        #pragma unroll
        for (int mi = 0; mi < 4; ++mi)
            af[mi] = *(const bf16x8*)(lA + (wm * 64 + mi * 16 + fr) * 32 + kc);
        #pragma unroll
        for (int ni = 0; ni < 4; ++ni)
            bfr[ni] = *(const bf16x8*)(lB + (wn * 64 + ni * 16 + fr) * 32 + kc);
        #pragma unroll
        for (int mi = 0; mi < 4; ++mi)
            #pragma unroll
            for (int ni = 0; ni < 4; ++ni)
                acc[mi][ni] = __builtin_amdgcn_mfma_f32_16x16x32_bf16(af[mi], bfr[ni], acc[mi][ni], 0, 0, 0);
    }
    const int orow = (lane >> 4) * 4;
    #pragma unroll
    for (int mi = 0; mi < 4; ++mi)
        #pragma unroll
        for (int ni = 0; ni < 4; ++ni) {
            int gm = m0 + wm * 64 + mi * 16 + orow;
            int gn = n0 + wn * 64 + ni * 16 + fr;
            float bo = bout[gn];
            if (bfmode) {
                #pragma unroll
                for (int j = 0; j < 4; ++j)
                    lgbf[(size_t)(gm + j) * 32000 + gn] = f2bf(acc[mi][ni][j] + bo);
            } else {
                #pragma unroll
                for (int j = 0; j < 4; ++j)
                    out[(size_t)(gm + j) * 32000 + gn] = acc[mi][ni][j] + bo;
            }
        }
}

// ---------------- row softmax, f32 in-place variant (r15-proven) ----------------
__global__ __launch_bounds__(512) void softmax_kernel(float* __restrict__ out) {
    __shared__ __align__(16) float row[32000];
    __shared__ float red[8];
    const int tid = threadIdx.x;
    float* p = out + (size_t)blockIdx.x * 32000;
    float mx = -3.4e38f;
    for (int c = tid; c < 8000; c += 512) {
        f32x4 v = *(const f32x4*)(p + c * 4);
        *(f32x4*)(row + c * 4) = v;
        mx = fmaxf(mx, fmaxf(fmaxf(v.x, v.y), fmaxf(v.z, v.w)));
    }
    #pragma unroll
    for (int o = 32; o; o >>= 1) mx = fmaxf(mx, __shfl_xor(mx, o, 64));
    if ((tid & 63) == 0) red[tid >> 6] = mx;
    __syncthreads();
    if (tid == 0) {
        float m = red[0];
        for (int i = 1; i < 8; ++i) m = fmaxf(m, red[i]);
        red[0] = m;
    }
    __syncthreads();
    mx = red[0];
    __syncthreads();
    float s = 0.f;
    for (int c = tid; c < 8000; c += 512) {
        f32x4 v = *(f32x4*)(row + c * 4);
        v.x = __expf(v.x - mx); v.y = __expf(v.y - mx);
        v.z = __expf(v.z - mx); v.w = __expf(v.w - mx);
        *(f32x4*)(row + c * 4) = v;
        s += v.x + v.y + v.z + v.w;
    }
    #pragma unroll
    for (int o = 32; o; o >>= 1) s += __shfl_xor(s, o, 64);
    if ((tid & 63) == 0) red[tid >> 6] = s;
    __syncthreads();
    if (tid == 0) {
        float t2 = 0.f;
        for (int i = 0; i < 8; ++i) t2 += red[i];
        red[0] = t2;
    }
    __syncthreads();
    float inv = 1.f / red[0];
    for (int c = tid; c < 8000; c += 512) {
        f32x4 v = *(f32x4*)(row + c * 4);
        v.x *= inv; v.y *= inv; v.z *= inv; v.w *= inv;
        *(f32x4*)(p + c * 4) = v;
    }
}

// ---------------- row softmax, bf16-logits-in / f32-probs-out variant ----------------
__global__ __launch_bounds__(512) void softmax_bf16(const unsigned short* __restrict__ lgbf,
                                                    float* __restrict__ out) {
    __shared__ __align__(16) float row[32000];
    __shared__ float red[8];
    const int tid = threadIdx.x;
    const unsigned short* lp = lgbf + (size_t)blockIdx.x * 32000;
    float* p = out + (size_t)blockIdx.x * 32000;
    float mx = -3.4e38f;
    for (int c = tid; c < 4000; c += 512) {            // 8 bf16 per thread per iter
        u16x8 v = *(const u16x8*)(lp + c * 8);
        #pragma unroll
        for (int q = 0; q < 8; ++q) {
            float f = bf2f(v[q]);
            row[c * 8 + q] = f;
            mx = fmaxf(mx, f);
        }
    }
    #pragma unroll
    for (int o = 32; o; o >>= 1) mx = fmaxf(mx, __shfl_xor(mx, o, 64));
    if ((tid & 63) == 0) red[tid >> 6] = mx;
    __syncthreads();
    if (tid == 0) {
        float m = red[0];
        for (int i = 1; i < 8; ++i) m = fmaxf(m, red[i]);
        red[0] = m;
    }
    __syncthreads();
    mx = red[0];
    __syncthreads();
    float s = 0.f;
    for (int c = tid; c < 8000; c += 512) {
        f32x4 v = *(f32x4*)(row + c * 4);
        v.x = __expf(v.x - mx); v.y = __expf(v.y - mx);
        v.z = __expf(v.z - mx); v.w = __expf(v.w - mx);
        *(f32x4*)(row + c * 4) = v;
        s += v.x + v.y + v.z + v.w;
    }
    #pragma unroll
    for (int o = 32; o; o >>= 1) s += __shfl_xor(s, o, 64);
    if ((tid & 63) == 0) red[tid >> 6] = s;
    __syncthreads();
    if (tid == 0) {
        float t2 = 0.f;
        for (int i = 0; i < 8; ++i) t2 += red[i];
        red[0] = t2;
    }
    __syncthreads();
    float inv = 1.f / red[0];
    for (int c = tid; c < 8000; c += 512) {
        f32x4 v = *(f32x4*)(row + c * 4);
        v.x *= inv; v.y *= inv; v.z *= inv; v.w *= inv;
        *(f32x4*)(p + c * 4) = v;
    }
}

extern "C" void kernel_launch(void* const* d_in, const int* in_sizes, int n_in,
                              void* d_out, int out_size, void* d_ws, size_t ws_size,
                              hipStream_t stream) {
    (void)in_sizes; (void)n_in; (void)out_size;
    const float* x    = (const float*)d_in[0];
    const float* eps  = (const float*)d_in[1];
    const float* eWih = (const float*)d_in[2];
    const float* eWhh = (const float*)d_in[3];
    const float* ebih = (const float*)d_in[4];
    const float* ebhh = (const float*)d_in[5];
    const float* Wmu  = (const float*)d_in[6];
    const float* bmu  = (const float*)d_in[7];
    const float* Wlv  = (const float*)d_in[8];
    const float* blv  = (const float*)d_in[9];
    const float* dWih = (const float*)d_in[10];
    const float* dWhh = (const float*)d_in[11];
    const float* dbih = (const float*)d_in[12];
    const float* dbhh = (const float*)d_in[13];
    const float* Wout = (const float*)d_in[14];
    const float* bout = (const float*)d_in[15];
    float* out = (float*)d_out;

    // workspace layout (base ~42.9 MB); bf16-logits path adds 262 MB if ws_size permits
    char* ws = (char*)d_ws;
    unsigned* ctrl         = (unsigned*)ws;                         // 64 KB reserved (init-zeroed)
    unsigned short* x_bf   = (unsigned short*)(ws + 65536);         // 4 MB
    unsigned short* ysbf   = x_bf + (size_t)16 * 256 * 512;         // 4 MB (wih_bf before dec)
    unsigned short* ring_e = ysbf + (size_t)4096 * 512;             // 512 KB
    unsigned short* ring_d = ring_e + (size_t)8 * 2 * 16384;        // 256 KB
    unsigned short* z_ring = ring_d + (size_t)8 * 2 * 8192;         // 16 KB
    float* hT              = (float*)(z_ring + 8192);               // 64 KB
    unsigned short* gxe    = (unsigned short*)(hT + 16384);         // 33.5 MB (gxe; reused as wo_bf)
    unsigned short* wih_bf = ysbf;                                  // eWih bf16 (dead once dec starts)
    unsigned short* wo_bf  = gxe;                                   // Wout bf16 (after enc)
    const size_t base_end  = 65536 + 4194304 + 4194304 + 524288 + 262144 + 16384 + 65536 + 33554432;
    const size_t lg_bytes  = (size_t)4096 * 32000 * 2;              // 262.1 MB
    const int bfmode       = (ws_size >= base_end + lg_bytes) ? 1 : 0;
    unsigned short* lg_bf  = (unsigned short*)(ws + base_end);      // valid only when bfmode

    hipLaunchKernelGGL(init_kernel, dim3(33), dim3(256), 0, stream, ctrl);
    hipLaunchKernelGGL(cvt_f32_bf16, dim3(2048), dim3(256), 0, stream, x, x_bf, 524288);
    hipLaunchKernelGGL(cvt_f32_bf16, dim3(2048), dim3(256), 0, stream, eWih, wih_bf, 524288);
    hipLaunchKernelGGL(gemm_gx, dim3(1024), dim3(256), 0, stream, x_bf, wih_bf, gxe, 4096);
    hipLaunchKernelGGL(enc_kernel, dim3(GRID_LSTM), dim3(256), 0, stream,
                       eWhh, ebih, ebhh, gxe, ring_e, hT, ctrl);
    hipLaunchKernelGGL(cvt_f32_bf16, dim3(16000), dim3(256), 0, stream, Wout, wo_bf, 4096000);
    hipLaunchKernelGGL(mlz_kernel, dim3(32), dim3(256), 0, stream,
                       hT, Wmu, bmu, Wlv, blv, eps, z_ring, out + 131072000);
    hipLaunchKernelGGL(dec_kernel, dim3(GRID_LSTM), dim3(256), 0, stream,
                       dWih, dWhh, dbih, dbhh, x_bf, z_ring, ring_d, ysbf, ctrl);
    hipLaunchKernelGGL(gemm_logits, dim3(8000), dim3(256), 0, stream,
                       ysbf, wo_bf, bout, out, lg_bf, bfmode);
    if (bfmode)
        hipLaunchKernelGGL(softmax_bf16, dim3(4096), dim3(512), 0, stream, lg_bf, out);
    else
        hipLaunchKernelGGL(softmax_kernel, dim3(4096), dim3(512), 0, stream, out);
}